// Round 1
// baseline (813.359 us; speedup 1.0000x reference)
//
#include <hip/hip_runtime.h>

#define S_LEN 577
#define DMODEL 768
#define NH 12
#define DHEAD 64
#define MLPD 3072
#define NROWS (32 * 577)      // 18464
#define MPAD  18560           // 145*128
#define NBH   (32 * 12)       // 384

typedef __attribute__((ext_vector_type(8))) short s8v;
typedef __attribute__((ext_vector_type(4))) float f4v;

#define MFMA16(a, b, c) __builtin_amdgcn_mfma_f32_16x16x32_bf16((a), (b), (c), 0, 0, 0)

__device__ __forceinline__ short f2bf(float f) {
  union { float f; unsigned u; } a; a.f = f;
  unsigned r = a.u + 0x7FFFu + ((a.u >> 16) & 1u);
  return (short)(r >> 16);
}

// ---------------- prep: transpose fp32 (R,C) -> bf16 (C,R) ----------------
__global__ __launch_bounds__(256) void transpose_w(const float* __restrict__ in,
                                                   short* __restrict__ out, int R, int C) {
  __shared__ float tile[32][33];
  int c0 = blockIdx.x * 32, r0 = blockIdx.y * 32;
  int tx = threadIdx.x, ty = threadIdx.y;
  for (int i = ty; i < 32; i += 8) tile[i][tx] = in[(size_t)(r0 + i) * C + c0 + tx];
  __syncthreads();
  for (int i = ty; i < 32; i += 8) out[(size_t)(c0 + i) * R + r0 + tx] = f2bf(tile[tx][i]);
}

// ---------------- prep: per-head (d,o) -> bf16 (o,d) for wq/wk/wv ----------------
__global__ __launch_bounds__(256) void prep_qkv(const float* __restrict__ wq, const float* __restrict__ wk,
                                                const float* __restrict__ wv, short* __restrict__ oq,
                                                short* __restrict__ ok, short* __restrict__ ov) {
  int h = blockIdx.x, t = threadIdx.x;
  const float* src0 = wq + (size_t)h * 4096;
  const float* src1 = wk + (size_t)h * 4096;
  const float* src2 = wv + (size_t)h * 4096;
  short* dst0 = oq + (size_t)h * 4096;
  short* dst1 = ok + (size_t)h * 4096;
  short* dst2 = ov + (size_t)h * 4096;
  for (int i = t; i < 4096; i += 256) {
    int o = i >> 6, d = i & 63;
    dst0[i] = f2bf(src0[d * 64 + o]);
    dst1[i] = f2bf(src1[d * 64 + o]);
    dst2[i] = f2bf(src2[d * 64 + o]);
  }
}

// ---------------- LayerNorm (D=768), fp32 in -> bf16 out ----------------
__global__ __launch_bounds__(256) void ln_kernel(const float* __restrict__ x, const float* __restrict__ g,
                                                 const float* __restrict__ bta, short* __restrict__ out) {
  int row = blockIdx.x;
  int t = threadIdx.x;
  const float* xr = x + (size_t)row * DMODEL;
  float v0 = xr[t], v1 = xr[t + 256], v2 = xr[t + 512];
  float s = v0 + v1 + v2;
  float s2 = v0 * v0 + v1 * v1 + v2 * v2;
  for (int o = 32; o; o >>= 1) { s += __shfl_down(s, o); s2 += __shfl_down(s2, o); }
  __shared__ float red[8];
  if ((t & 63) == 0) { int w = t >> 6; red[w] = s; red[4 + w] = s2; }
  __syncthreads();
  s = red[0] + red[1] + red[2] + red[3];
  s2 = red[4] + red[5] + red[6] + red[7];
  float m = s * (1.f / DMODEL);
  float rs = rsqrtf(s2 * (1.f / DMODEL) - m * m + 1e-5f);
  short* orow = out + (size_t)row * DMODEL;
  orow[t]       = f2bf((v0 - m) * rs * g[t]       + bta[t]);
  orow[t + 256] = f2bf((v1 - m) * rs * g[t + 256] + bta[t + 256]);
  orow[t + 512] = f2bf((v2 - m) * rs * g[t + 512] + bta[t + 512]);
}

// ---------------- QKV: per-head 64x64 GEMM, bias, q pre-scaled 1/8 ----------------
__global__ __launch_bounds__(256) void qkv_kernel(const short* __restrict__ xn,
    const short* __restrict__ wqt, const short* __restrict__ wkt, const short* __restrict__ wvt,
    const float* __restrict__ bq, const float* __restrict__ bk, const float* __restrict__ bv,
    short* __restrict__ qg, short* __restrict__ kg, short* __restrict__ vg) {
  __shared__ __align__(16) short wl[3][64][72];
  int bid = blockIdx.x;
  int h = bid % NH, mt = bid / NH;
  int t = threadIdx.x;
  {
    int o = t >> 2, d0 = (t & 3) * 16;
    const short* s0 = wqt + (size_t)h * 4096 + o * 64 + d0;
    const short* s1 = wkt + (size_t)h * 4096 + o * 64 + d0;
    const short* s2 = wvt + (size_t)h * 4096 + o * 64 + d0;
    *(uint4*)&wl[0][o][d0]     = *(const uint4*)s0;
    *(uint4*)&wl[0][o][d0 + 8] = *(const uint4*)(s0 + 8);
    *(uint4*)&wl[1][o][d0]     = *(const uint4*)s1;
    *(uint4*)&wl[1][o][d0 + 8] = *(const uint4*)(s1 + 8);
    *(uint4*)&wl[2][o][d0]     = *(const uint4*)s2;
    *(uint4*)&wl[2][o][d0 + 8] = *(const uint4*)(s2 + 8);
  }
  __syncthreads();
  int w = t >> 6, l = t & 63, l15 = l & 15, lh = l >> 4;
  int m0 = mt * 64 + w * 16;
  if (m0 >= NROWS) return;
  f4v z = {0.f, 0.f, 0.f, 0.f};
  f4v aq[4], ak[4], av[4];
#pragma unroll
  for (int nt = 0; nt < 4; ++nt) { aq[nt] = z; ak[nt] = z; av[nt] = z; }
  const short* xrow = xn + (size_t)(m0 + l15) * DMODEL + h * DHEAD;
#pragma unroll
  for (int kk = 0; kk < 64; kk += 32) {
    s8v af = *(const s8v*)(xrow + kk + lh * 8);
#pragma unroll
    for (int nt = 0; nt < 4; ++nt) {
      s8v b0 = *(const s8v*)&wl[0][nt * 16 + l15][kk + lh * 8];
      s8v b1 = *(const s8v*)&wl[1][nt * 16 + l15][kk + lh * 8];
      s8v b2 = *(const s8v*)&wl[2][nt * 16 + l15][kk + lh * 8];
      aq[nt] = MFMA16(af, b0, aq[nt]);
      ak[nt] = MFMA16(af, b1, ak[nt]);
      av[nt] = MFMA16(af, b2, av[nt]);
    }
  }
#pragma unroll
  for (int nt = 0; nt < 4; ++nt) {
    int col = nt * 16 + l15;
    float biq = bq[h * DHEAD + col], bik = bk[h * DHEAD + col], biv = bv[h * DHEAD + col];
#pragma unroll
    for (int i = 0; i < 4; ++i) {
      int m = m0 + lh * 4 + i;
      int bb = m / S_LEN;
      int ss = m - bb * S_LEN;
      size_t ob = (((size_t)bb * NH + h) * S_LEN + ss) * DHEAD + col;
      qg[ob] = f2bf((aq[nt][i] + biq) * 0.125f);
      kg[ob] = f2bf(ak[nt][i] + bik);
      vg[ob] = f2bf(av[nt][i] + biv);
    }
  }
}

// ---------------- attention: block per (16-row q-tile, b*h); fused x + o -> out ----------------
__global__ __launch_bounds__(256) void attn_kernel(const short* __restrict__ qg, const short* __restrict__ kg,
                                                   const short* __restrict__ vg, const float* __restrict__ x,
                                                   float* __restrict__ outp) {
  int qt = blockIdx.x;       // 0..36
  int bh = blockIdx.y;       // 0..383
  int h = bh % NH, b = bh / NH;
  __shared__ __align__(16) float sc[16][580];
  __shared__ __align__(16) short P[16][616];
  __shared__ float rinv[16];
  int t = threadIdx.x, w = t >> 6, l = t & 63, l15 = l & 15, lh = l >> 4;
  size_t base = (size_t)bh * S_LEN * DHEAD;
  f4v z = {0.f, 0.f, 0.f, 0.f};

  // phase 1: scores = q' . k  (q pre-scaled by 1/8)
  int qrow = qt * 16 + l15; if (qrow > 576) qrow = 576;
  s8v aq0 = *(const s8v*)(qg + base + (size_t)qrow * DHEAD + lh * 8);
  s8v aq1 = *(const s8v*)(qg + base + (size_t)qrow * DHEAD + 32 + lh * 8);
  for (int kt = w; kt < 37; kt += 4) {
    int key = kt * 16 + l15; if (key > 576) key = 576;
    s8v b0 = *(const s8v*)(kg + base + (size_t)key * DHEAD + lh * 8);
    s8v b1 = *(const s8v*)(kg + base + (size_t)key * DHEAD + 32 + lh * 8);
    f4v acc = z;
    acc = MFMA16(aq0, b0, acc);
    acc = MFMA16(aq1, b1, acc);
#pragma unroll
    for (int i = 0; i < 4; ++i) {
      int row = lh * 4 + i, col = kt * 16 + l15;
      if (col < S_LEN) sc[row][col] = acc[i];
    }
  }
  __syncthreads();

  // phase 2: softmax (unnormalized P in bf16, row 1/sum saved)
  {
    int r = t >> 4, sub = t & 15;
    float mx = -1e30f;
    for (int c = sub; c < S_LEN; c += 16) mx = fmaxf(mx, sc[r][c]);
    for (int o = 1; o < 16; o <<= 1) mx = fmaxf(mx, __shfl_xor(mx, o));
    float sum = 0.f;
    for (int c = sub; c < 608; c += 16) {
      float e = 0.f;
      if (c < S_LEN) { e = __expf(sc[r][c] - mx); sum += e; }
      P[r][c] = f2bf(e);
    }
    for (int o = 1; o < 16; o <<= 1) sum += __shfl_xor(sum, o);
    if (sub == 0) rinv[r] = 1.f / sum;
  }
  __syncthreads();

  // phase 3: O = P @ V, wave w owns output cols w*16..w*16+15
  int n0 = w * 16;
  f4v acc = z;
  for (int ks = 0; ks < 19; ++ks) {
    int kb = ks * 32;
    s8v bf;
#pragma unroll
    for (int j = 0; j < 8; ++j) {
      int key = kb + lh * 8 + j; if (key > 576) key = 576;
      bf[j] = vg[base + (size_t)key * DHEAD + n0 + l15];
    }
    s8v af = *(const s8v*)&P[l15][kb + lh * 8];
    acc = MFMA16(af, bf, acc);
  }
#pragma unroll
  for (int i = 0; i < 4; ++i) {
    int row = lh * 4 + i;
    int s = qt * 16 + row;
    if (s < S_LEN) {
      size_t idx = ((size_t)b * S_LEN + s) * DMODEL + h * DHEAD + n0 + l15;
      outp[idx] = x[idx] + acc[i] * rinv[row];
    }
  }
}

// ---------------- 128x128 bf16 MFMA GEMM + bias + erf-GELU -> bf16 ----------------
__global__ __launch_bounds__(256) void gemm_gelu(const short* __restrict__ A, const short* __restrict__ Bt,
                                                 const float* __restrict__ bias, short* __restrict__ C,
                                                 int M, int N, int K) {
  __shared__ __align__(16) short sA[128][72];
  __shared__ __align__(16) short sB[128][72];
  int m0 = blockIdx.x * 128, n0 = blockIdx.y * 128;
  int t = threadIdx.x;
  int w = t >> 6, l = t & 63, l15 = l & 15, lh = l >> 4;
  int wr = w >> 1, wc = w & 1;
  int tr = t >> 3, tc = (t & 7) << 3;
  f4v z = {0.f, 0.f, 0.f, 0.f};
  f4v acc[4][4];
#pragma unroll
  for (int i = 0; i < 4; ++i)
#pragma unroll
    for (int j = 0; j < 4; ++j) acc[i][j] = z;
  for (int k0 = 0; k0 < K; k0 += 64) {
    __syncthreads();
#pragma unroll
    for (int c = 0; c < 4; ++c) {
      int row = tr + c * 32;
      *(uint4*)&sA[row][tc] = *(const uint4*)(A + (size_t)(m0 + row) * K + k0 + tc);
      *(uint4*)&sB[row][tc] = *(const uint4*)(Bt + (size_t)(n0 + row) * K + k0 + tc);
    }
    __syncthreads();
#pragma unroll
    for (int kk = 0; kk < 64; kk += 32) {
      s8v af[4], bf[4];
#pragma unroll
      for (int mt = 0; mt < 4; ++mt) af[mt] = *(const s8v*)&sA[wr * 64 + mt * 16 + l15][kk + lh * 8];
#pragma unroll
      for (int nt = 0; nt < 4; ++nt) bf[nt] = *(const s8v*)&sB[wc * 64 + nt * 16 + l15][kk + lh * 8];
#pragma unroll
      for (int mt = 0; mt < 4; ++mt)
#pragma unroll
        for (int nt = 0; nt < 4; ++nt) acc[mt][nt] = MFMA16(af[mt], bf[nt], acc[mt][nt]);
    }
  }
#pragma unroll
  for (int mt = 0; mt < 4; ++mt)
#pragma unroll
    for (int nt = 0; nt < 4; ++nt) {
      int col = n0 + wc * 64 + nt * 16 + l15;
      float bi = bias[col];
#pragma unroll
      for (int i = 0; i < 4; ++i) {
        int row = m0 + wr * 64 + mt * 16 + lh * 4 + i;
        float v = acc[mt][nt][i] + bi;
        v = 0.5f * v * (1.f + erff(v * 0.70710678118654752f));
        C[(size_t)row * N + col] = f2bf(v);
      }
    }
}

// ---------------- 128x128 bf16 MFMA GEMM + bias + residual (in-place on out) ----------------
__global__ __launch_bounds__(256) void gemm_res(const short* __restrict__ A, const short* __restrict__ Bt,
                                                const float* __restrict__ bias, float* __restrict__ outp,
                                                int Mvalid, int N, int K) {
  __shared__ __align__(16) short sA[128][72];
  __shared__ __align__(16) short sB[128][72];
  int m0 = blockIdx.x * 128, n0 = blockIdx.y * 128;
  int t = threadIdx.x;
  int w = t >> 6, l = t & 63, l15 = l & 15, lh = l >> 4;
  int wr = w >> 1, wc = w & 1;
  int tr = t >> 3, tc = (t & 7) << 3;
  f4v z = {0.f, 0.f, 0.f, 0.f};
  f4v acc[4][4];
#pragma unroll
  for (int i = 0; i < 4; ++i)
#pragma unroll
    for (int j = 0; j < 4; ++j) acc[i][j] = z;
  for (int k0 = 0; k0 < K; k0 += 64) {
    __syncthreads();
#pragma unroll
    for (int c = 0; c < 4; ++c) {
      int row = tr + c * 32;
      *(uint4*)&sA[row][tc] = *(const uint4*)(A + (size_t)(m0 + row) * K + k0 + tc);
      *(uint4*)&sB[row][tc] = *(const uint4*)(Bt + (size_t)(n0 + row) * K + k0 + tc);
    }
    __syncthreads();
#pragma unroll
    for (int kk = 0; kk < 64; kk += 32) {
      s8v af[4], bf[4];
#pragma unroll
      for (int mt = 0; mt < 4; ++mt) af[mt] = *(const s8v*)&sA[wr * 64 + mt * 16 + l15][kk + lh * 8];
#pragma unroll
      for (int nt = 0; nt < 4; ++nt) bf[nt] = *(const s8v*)&sB[wc * 64 + nt * 16 + l15][kk + lh * 8];
#pragma unroll
      for (int mt = 0; mt < 4; ++mt)
#pragma unroll
        for (int nt = 0; nt < 4; ++nt) acc[mt][nt] = MFMA16(af[mt], bf[nt], acc[mt][nt]);
    }
  }
#pragma unroll
  for (int mt = 0; mt < 4; ++mt)
#pragma unroll
    for (int nt = 0; nt < 4; ++nt) {
      int col = n0 + wc * 64 + nt * 16 + l15;
      float bi = bias[col];
#pragma unroll
      for (int i = 0; i < 4; ++i) {
        int row = m0 + wr * 64 + mt * 16 + lh * 4 + i;
        if (row < Mvalid) {
          size_t idx = (size_t)row * N + col;
          outp[idx] += acc[mt][nt][i] + bi;
        }
      }
    }
}

extern "C" void kernel_launch(void* const* d_in, const int* in_sizes, int n_in,
                              void* d_out, int out_size, void* d_ws, size_t ws_size,
                              hipStream_t stream) {
  const float* x    = (const float*)d_in[0];
  const float* ln1g = (const float*)d_in[1];
  const float* ln1b = (const float*)d_in[2];
  const float* ln2g = (const float*)d_in[3];
  const float* ln2b = (const float*)d_in[4];
  const float* wq   = (const float*)d_in[5];
  const float* bq   = (const float*)d_in[6];
  const float* wk   = (const float*)d_in[7];
  const float* bk   = (const float*)d_in[8];
  const float* wv   = (const float*)d_in[9];
  const float* bv   = (const float*)d_in[10];
  const float* w1   = (const float*)d_in[11];
  const float* b1   = (const float*)d_in[12];
  const float* w2   = (const float*)d_in[13];
  const float* b2   = (const float*)d_in[14];
  float* outp = (float*)d_out;

  char* ws = (char*)d_ws;
  size_t off = 0;
  auto alloc = [&](size_t elems) -> short* {
    short* p = (short*)(ws + off);
    off += elems * sizeof(short);
    off = (off + 255) & ~(size_t)255;
    return p;
  };
  short* xn   = alloc((size_t)NROWS * DMODEL);
  short* qg   = alloc((size_t)NBH * S_LEN * DHEAD);
  short* kg   = alloc((size_t)NBH * S_LEN * DHEAD);
  short* vg   = alloc((size_t)NBH * S_LEN * DHEAD);
  short* yn   = alloc((size_t)MPAD * DMODEL);
  short* hbuf = alloc((size_t)MPAD * MLPD);
  short* w1t  = alloc((size_t)MLPD * DMODEL);
  short* w2t  = alloc((size_t)DMODEL * MLPD);
  short* wqt  = alloc((size_t)NH * 64 * 64);
  short* wkt  = alloc((size_t)NH * 64 * 64);
  short* wvt  = alloc((size_t)NH * 64 * 64);
  (void)ws_size; (void)in_sizes; (void)n_in; (void)out_size;

  // prep weights
  transpose_w<<<dim3(MLPD / 32, DMODEL / 32), dim3(32, 8), 0, stream>>>(w1, w1t, DMODEL, MLPD);
  transpose_w<<<dim3(DMODEL / 32, MLPD / 32), dim3(32, 8), 0, stream>>>(w2, w2t, MLPD, DMODEL);
  prep_qkv<<<NH, 256, 0, stream>>>(wq, wk, wv, wqt, wkt, wvt);

  // LN1 -> xn (bf16)
  ln_kernel<<<NROWS, 256, 0, stream>>>(x, ln1g, ln1b, xn);

  // QKV projections
  qkv_kernel<<<((NROWS + 63) / 64) * NH, 256, 0, stream>>>(xn, wqt, wkt, wvt, bq, bk, bv, qg, kg, vg);

  // attention + residual1 -> d_out
  attn_kernel<<<dim3(37, NBH), 256, 0, stream>>>(qg, kg, vg, x, outp);

  // LN2 -> yn (bf16, padded rows untouched)
  ln_kernel<<<NROWS, 256, 0, stream>>>(outp, ln2g, ln2b, yn);

  // MLP
  gemm_gelu<<<dim3(MPAD / 128, MLPD / 128), 256, 0, stream>>>(yn, w1t, b1, hbuf, MPAD, MLPD, DMODEL);
  gemm_res<<<dim3(MPAD / 128, DMODEL / 128), 256, 0, stream>>>(hbuf, w2t, b2, outp, NROWS, DMODEL, MLPD);
}

// Round 3
// 725.439 us; speedup vs baseline: 1.1212x; 1.1212x over previous
//
#include <hip/hip_runtime.h>

#define S_LEN 577
#define SPAD  640
#define DMODEL 768
#define NH 12
#define DHEAD 64
#define MLPD 3072
#define NROWS (32 * 577)      // 18464
#define MPAD  18560           // 145*128
#define NBH   (32 * 12)       // 384

typedef __attribute__((ext_vector_type(8))) short s8v;
typedef __attribute__((ext_vector_type(4))) float f4v;

#define MFMA16(a, b, c) __builtin_amdgcn_mfma_f32_16x16x32_bf16((a), (b), (c), 0, 0, 0)

__device__ __forceinline__ short f2bf(float f) {
  union { float f; unsigned u; } a; a.f = f;
  unsigned r = a.u + 0x7FFFu + ((a.u >> 16) & 1u);
  return (short)(r >> 16);
}

__device__ __forceinline__ void gload16(const short* g, const short* l) {
  __builtin_amdgcn_global_load_lds(
      (const __attribute__((address_space(1))) void*)g,
      (__attribute__((address_space(3))) void*)l, 16, 0, 0);
}

// ---------------- prep: transpose fp32 (R,C) -> bf16 (C,R) ----------------
__global__ __launch_bounds__(256) void transpose_w(const float* __restrict__ in,
                                                   short* __restrict__ out, int R, int C) {
  __shared__ float tile[32][33];
  int c0 = blockIdx.x * 32, r0 = blockIdx.y * 32;
  int tx = threadIdx.x, ty = threadIdx.y;
  for (int i = ty; i < 32; i += 8) tile[i][tx] = in[(size_t)(r0 + i) * C + c0 + tx];
  __syncthreads();
  for (int i = ty; i < 32; i += 8) out[(size_t)(c0 + i) * R + r0 + tx] = f2bf(tile[tx][i]);
}

// ---------------- prep: per-head (d,o) -> bf16 (o,d) for wq/wk/wv ----------------
__global__ __launch_bounds__(256) void prep_qkv(const float* __restrict__ wq, const float* __restrict__ wk,
                                                const float* __restrict__ wv, short* __restrict__ oq,
                                                short* __restrict__ ok, short* __restrict__ ov) {
  int h = blockIdx.x, t = threadIdx.x;
  const float* src0 = wq + (size_t)h * 4096;
  const float* src1 = wk + (size_t)h * 4096;
  const float* src2 = wv + (size_t)h * 4096;
  short* dst0 = oq + (size_t)h * 4096;
  short* dst1 = ok + (size_t)h * 4096;
  short* dst2 = ov + (size_t)h * 4096;
  for (int i = t; i < 4096; i += 256) {
    int o = i >> 6, d = i & 63;
    dst0[i] = f2bf(src0[d * 64 + o]);
    dst1[i] = f2bf(src1[d * 64 + o]);
    dst2[i] = f2bf(src2[d * 64 + o]);
  }
}

// ---------------- zero the s-padding of vt: [NBH][64][SPAD], s in [577,640) ----------------
__global__ __launch_bounds__(256) void pad_vt(short* __restrict__ vt) {
  int idx = blockIdx.x * 256 + threadIdx.x;
  const int padw = SPAD - S_LEN;          // 63
  const int per = DHEAD * padw;           // 4032
  if (idx >= NBH * per) return;
  int bh = idx / per, r = idx - bh * per;
  int col = r / padw, s = S_LEN + (r - col * padw);
  vt[((size_t)bh * DHEAD + col) * SPAD + s] = 0;
}

// ---------------- LayerNorm (D=768), fp32 in -> bf16 out ----------------
__global__ __launch_bounds__(256) void ln_kernel(const float* __restrict__ x, const float* __restrict__ g,
                                                 const float* __restrict__ bta, short* __restrict__ out) {
  int row = blockIdx.x;
  int t = threadIdx.x;
  const float* xr = x + (size_t)row * DMODEL;
  float v0 = xr[t], v1 = xr[t + 256], v2 = xr[t + 512];
  float s = v0 + v1 + v2;
  float s2 = v0 * v0 + v1 * v1 + v2 * v2;
  for (int o = 32; o; o >>= 1) { s += __shfl_down(s, o); s2 += __shfl_down(s2, o); }
  __shared__ float red[8];
  if ((t & 63) == 0) { int w = t >> 6; red[w] = s; red[4 + w] = s2; }
  __syncthreads();
  s = red[0] + red[1] + red[2] + red[3];
  s2 = red[4] + red[5] + red[6] + red[7];
  float m = s * (1.f / DMODEL);
  float rs = rsqrtf(s2 * (1.f / DMODEL) - m * m + 1e-5f);
  short* orow = out + (size_t)row * DMODEL;
  orow[t]       = f2bf((v0 - m) * rs * g[t]       + bta[t]);
  orow[t + 256] = f2bf((v1 - m) * rs * g[t + 256] + bta[t + 256]);
  orow[t + 512] = f2bf((v2 - m) * rs * g[t + 512] + bta[t + 512]);
}

// ---------------- QKV: per-head 64x64 GEMM, bias; q pre-scaled 1/8; V written transposed ----------------
__global__ __launch_bounds__(256) void qkv_kernel(const short* __restrict__ xn,
    const short* __restrict__ wqt, const short* __restrict__ wkt, const short* __restrict__ wvt,
    const float* __restrict__ bq, const float* __restrict__ bk, const float* __restrict__ bv,
    short* __restrict__ qg, short* __restrict__ kg, short* __restrict__ vt) {
  __shared__ __align__(16) short wl[3][64][72];
  int bid = blockIdx.x;
  int h = bid % NH, mt = bid / NH;
  int t = threadIdx.x;
  {
    int o = t >> 2, d0 = (t & 3) * 16;
    const short* s0 = wqt + (size_t)h * 4096 + o * 64 + d0;
    const short* s1 = wkt + (size_t)h * 4096 + o * 64 + d0;
    const short* s2 = wvt + (size_t)h * 4096 + o * 64 + d0;
    *(uint4*)&wl[0][o][d0]     = *(const uint4*)s0;
    *(uint4*)&wl[0][o][d0 + 8] = *(const uint4*)(s0 + 8);
    *(uint4*)&wl[1][o][d0]     = *(const uint4*)s1;
    *(uint4*)&wl[1][o][d0 + 8] = *(const uint4*)(s1 + 8);
    *(uint4*)&wl[2][o][d0]     = *(const uint4*)s2;
    *(uint4*)&wl[2][o][d0 + 8] = *(const uint4*)(s2 + 8);
  }
  __syncthreads();
  int w = t >> 6, l = t & 63, l15 = l & 15, lh = l >> 4;
  int m0 = mt * 64 + w * 16;
  if (m0 >= NROWS) return;
  f4v z = {0.f, 0.f, 0.f, 0.f};
  f4v aq[4], ak[4], av[4];
#pragma unroll
  for (int nt = 0; nt < 4; ++nt) { aq[nt] = z; ak[nt] = z; av[nt] = z; }
  const short* xrow = xn + (size_t)(m0 + l15) * DMODEL + h * DHEAD;
#pragma unroll
  for (int kk = 0; kk < 64; kk += 32) {
    s8v af = *(const s8v*)(xrow + kk + lh * 8);
#pragma unroll
    for (int nt = 0; nt < 4; ++nt) {
      s8v b0 = *(const s8v*)&wl[0][nt * 16 + l15][kk + lh * 8];
      s8v b1 = *(const s8v*)&wl[1][nt * 16 + l15][kk + lh * 8];
      s8v b2 = *(const s8v*)&wl[2][nt * 16 + l15][kk + lh * 8];
      aq[nt] = MFMA16(af, b0, aq[nt]);
      ak[nt] = MFMA16(af, b1, ak[nt]);
      av[nt] = MFMA16(af, b2, av[nt]);
    }
  }
#pragma unroll
  for (int nt = 0; nt < 4; ++nt) {
    int col = nt * 16 + l15;
    float biq = bq[h * DHEAD + col], bik = bk[h * DHEAD + col], biv = bv[h * DHEAD + col];
#pragma unroll
    for (int i = 0; i < 4; ++i) {
      int m = m0 + lh * 4 + i;
      int bb = m / S_LEN;
      int ss = m - bb * S_LEN;
      int bh = bb * NH + h;
      size_t ob = ((size_t)bh * S_LEN + ss) * DHEAD + col;
      qg[ob] = f2bf((aq[nt][i] + biq) * 0.125f);
      kg[ob] = f2bf(ak[nt][i] + bik);
      vt[((size_t)bh * DHEAD + col) * SPAD + ss] = f2bf(av[nt][i] + biv);
    }
  }
}

// ---------------- attention: flash-style, block=(64 q-rows, bh), 4 independent waves ----------------
__global__ __launch_bounds__(256) void attn_kernel(const short* __restrict__ qg, const short* __restrict__ kg,
                                                   const short* __restrict__ vt, const float* __restrict__ x,
                                                   float* __restrict__ outp) {
  __shared__ __align__(16) short Pb[4][16][72];
  int qt = blockIdx.x;       // 0..9
  int bh = blockIdx.y;       // 0..383
  int h = bh % NH, b = bh / NH;
  int t = threadIdx.x, w = t >> 6, l = t & 63, l15 = l & 15, lh = l >> 4;
  int q0 = qt * 64 + w * 16;
  if (q0 > 576) return;
  size_t base  = (size_t)bh * S_LEN * DHEAD;
  size_t vbase = (size_t)bh * DHEAD * SPAD;
  int qrow = q0 + l15; if (qrow > 576) qrow = 576;
  s8v aq0 = *(const s8v*)(qg + base + (size_t)qrow * DHEAD + lh * 8);
  s8v aq1 = *(const s8v*)(qg + base + (size_t)qrow * DHEAD + 32 + lh * 8);
  f4v z = {0.f, 0.f, 0.f, 0.f};
  f4v acc_o[4];
  float mrow[4], lrow[4];
#pragma unroll
  for (int dt = 0; dt < 4; ++dt) acc_o[dt] = z;
#pragma unroll
  for (int i = 0; i < 4; ++i) { mrow[i] = -1e30f; lrow[i] = 0.f; }

  for (int kt = 0; kt < 10; ++kt) {
    int kb = kt * 64;
    // ---- scores S[16 q][64 k] ----
    f4v sc[4];
#pragma unroll
    for (int nt = 0; nt < 4; ++nt) {
      int key = kb + nt * 16 + l15; if (key > 576) key = 576;
      const short* kp = kg + base + (size_t)key * DHEAD + lh * 8;
      s8v b0 = *(const s8v*)kp;
      s8v b1 = *(const s8v*)(kp + 32);
      f4v a = z;
      a = MFMA16(aq0, b0, a);
      a = MFMA16(aq1, b1, a);
      sc[nt] = a;
    }
    if (kt == 9) {
#pragma unroll
      for (int nt = 0; nt < 4; ++nt) {
        int col = kb + nt * 16 + l15;
        if (col > 576) { sc[nt][0] = sc[nt][1] = sc[nt][2] = sc[nt][3] = -1e30f; }
      }
    }
    // ---- online softmax (rows = lh*4+i, reduce across l15 group) ----
    float p[4][4];
#pragma unroll
    for (int i = 0; i < 4; ++i) {
      float m2 = fmaxf(fmaxf(sc[0][i], sc[1][i]), fmaxf(sc[2][i], sc[3][i]));
      m2 = fmaxf(m2, __shfl_xor(m2, 1));
      m2 = fmaxf(m2, __shfl_xor(m2, 2));
      m2 = fmaxf(m2, __shfl_xor(m2, 4));
      m2 = fmaxf(m2, __shfl_xor(m2, 8));
      float mn = fmaxf(mrow[i], m2);
      float f = __expf(mrow[i] - mn);
      mrow[i] = mn;
      float sum = 0.f;
#pragma unroll
      for (int nt = 0; nt < 4; ++nt) { float e = __expf(sc[nt][i] - mn); p[nt][i] = e; sum += e; }
      sum += __shfl_xor(sum, 1);
      sum += __shfl_xor(sum, 2);
      sum += __shfl_xor(sum, 4);
      sum += __shfl_xor(sum, 8);
      lrow[i] = lrow[i] * f + sum;
#pragma unroll
      for (int dt = 0; dt < 4; ++dt) acc_o[dt][i] *= f;
    }
    // ---- P -> wave-private LDS (row=q, col=key) ----
#pragma unroll
    for (int nt = 0; nt < 4; ++nt)
#pragma unroll
      for (int i = 0; i < 4; ++i)
        Pb[w][lh * 4 + i][nt * 16 + l15] = f2bf(p[nt][i]);
    // ---- PV: O += P @ V ----
#pragma unroll
    for (int kk2 = 0; kk2 < 2; ++kk2) {
      s8v af = *(const s8v*)&Pb[w][l15][kk2 * 32 + lh * 8];
      const short* vp = vt + vbase + kb + kk2 * 32 + lh * 8;
#pragma unroll
      for (int dt = 0; dt < 4; ++dt) {
        s8v bf = *(const s8v*)(vp + (size_t)(dt * 16 + l15) * SPAD);
        acc_o[dt] = MFMA16(af, bf, acc_o[dt]);
      }
    }
  }
  // ---- epilogue: normalize + residual ----
#pragma unroll
  for (int i = 0; i < 4; ++i) {
    int srow = q0 + lh * 4 + i;
    if (srow > 576) continue;
    float inv = 1.f / lrow[i];
    size_t idx0 = ((size_t)b * S_LEN + srow) * DMODEL + h * DHEAD + l15;
#pragma unroll
    for (int dt = 0; dt < 4; ++dt) {
      size_t idx = idx0 + dt * 16;
      outp[idx] = x[idx] + acc_o[dt][i] * inv;
    }
  }
}

// ---------------- 128x128 bf16 MFMA GEMM (global_load_lds staging) + bias + erf-GELU ----------------
__global__ __launch_bounds__(256) void gemm_gelu(const short* __restrict__ A, const short* __restrict__ Bt,
                                                 const float* __restrict__ bias, short* __restrict__ C,
                                                 int M, int N, int K) {
  __shared__ __align__(16) short sA[128][64];
  __shared__ __align__(16) short sB[128][64];
  int m0 = blockIdx.x * 128, n0 = blockIdx.y * 128;
  int t = threadIdx.x;
  int w = t >> 6, l = t & 63, l15 = l & 15, lh = l >> 4;
  int wr = w >> 1, wc = w & 1;
  int lrow = l >> 3, lcol = (l & 7) * 8;
  f4v z = {0.f, 0.f, 0.f, 0.f};
  f4v acc[4][4];
#pragma unroll
  for (int i = 0; i < 4; ++i)
#pragma unroll
    for (int j = 0; j < 4; ++j) acc[i][j] = z;
  for (int k0 = 0; k0 < K; k0 += 64) {
    __syncthreads();
#pragma unroll
    for (int c = 0; c < 4; ++c) {
      int ch = w * 4 + c;                 // 0..15
      int row = ch * 8 + lrow;
      gload16(A  + (size_t)(m0 + row) * K + k0 + lcol, &sA[0][0] + ch * 512);
      gload16(Bt + (size_t)(n0 + row) * K + k0 + lcol, &sB[0][0] + ch * 512);
    }
    __syncthreads();
#pragma unroll
    for (int kk = 0; kk < 64; kk += 32) {
      s8v af[4], bf[4];
#pragma unroll
      for (int mt = 0; mt < 4; ++mt) af[mt] = *(const s8v*)&sA[wr * 64 + mt * 16 + l15][kk + lh * 8];
#pragma unroll
      for (int nt = 0; nt < 4; ++nt) bf[nt] = *(const s8v*)&sB[wc * 64 + nt * 16 + l15][kk + lh * 8];
#pragma unroll
      for (int mt = 0; mt < 4; ++mt)
#pragma unroll
        for (int nt = 0; nt < 4; ++nt) acc[mt][nt] = MFMA16(af[mt], bf[nt], acc[mt][nt]);
    }
  }
#pragma unroll
  for (int mt = 0; mt < 4; ++mt)
#pragma unroll
    for (int nt = 0; nt < 4; ++nt) {
      int col = n0 + wc * 64 + nt * 16 + l15;
      float bi = bias[col];
#pragma unroll
      for (int i = 0; i < 4; ++i) {
        int row = m0 + wr * 64 + mt * 16 + lh * 4 + i;
        float v = acc[mt][nt][i] + bi;
        v = 0.5f * v * (1.f + erff(v * 0.70710678118654752f));
        C[(size_t)row * N + col] = f2bf(v);
      }
    }
}

// ---------------- 128x128 bf16 MFMA GEMM (global_load_lds staging) + bias + residual ----------------
__global__ __launch_bounds__(256) void gemm_res(const short* __restrict__ A, const short* __restrict__ Bt,
                                                const float* __restrict__ bias, float* __restrict__ outp,
                                                int Mvalid, int N, int K) {
  __shared__ __align__(16) short sA[128][64];
  __shared__ __align__(16) short sB[128][64];
  int m0 = blockIdx.x * 128, n0 = blockIdx.y * 128;
  int t = threadIdx.x;
  int w = t >> 6, l = t & 63, l15 = l & 15, lh = l >> 4;
  int wr = w >> 1, wc = w & 1;
  int lrow = l >> 3, lcol = (l & 7) * 8;
  f4v z = {0.f, 0.f, 0.f, 0.f};
  f4v acc[4][4];
#pragma unroll
  for (int i = 0; i < 4; ++i)
#pragma unroll
    for (int j = 0; j < 4; ++j) acc[i][j] = z;
  for (int k0 = 0; k0 < K; k0 += 64) {
    __syncthreads();
#pragma unroll
    for (int c = 0; c < 4; ++c) {
      int ch = w * 4 + c;
      int row = ch * 8 + lrow;
      gload16(A  + (size_t)(m0 + row) * K + k0 + lcol, &sA[0][0] + ch * 512);
      gload16(Bt + (size_t)(n0 + row) * K + k0 + lcol, &sB[0][0] + ch * 512);
    }
    __syncthreads();
#pragma unroll
    for (int kk = 0; kk < 64; kk += 32) {
      s8v af[4], bf[4];
#pragma unroll
      for (int mt = 0; mt < 4; ++mt) af[mt] = *(const s8v*)&sA[wr * 64 + mt * 16 + l15][kk + lh * 8];
#pragma unroll
      for (int nt = 0; nt < 4; ++nt) bf[nt] = *(const s8v*)&sB[wc * 64 + nt * 16 + l15][kk + lh * 8];
#pragma unroll
      for (int mt = 0; mt < 4; ++mt)
#pragma unroll
        for (int nt = 0; nt < 4; ++nt) acc[mt][nt] = MFMA16(af[mt], bf[nt], acc[mt][nt]);
    }
  }
#pragma unroll
  for (int mt = 0; mt < 4; ++mt)
#pragma unroll
    for (int nt = 0; nt < 4; ++nt) {
      int col = n0 + wc * 64 + nt * 16 + l15;
      float bi = bias[col];
#pragma unroll
      for (int i = 0; i < 4; ++i) {
        int row = m0 + wr * 64 + mt * 16 + lh * 4 + i;
        if (row < Mvalid) {
          size_t idx = (size_t)row * N + col;
          outp[idx] += acc[mt][nt][i] + bi;
        }
      }
    }
}

extern "C" void kernel_launch(void* const* d_in, const int* in_sizes, int n_in,
                              void* d_out, int out_size, void* d_ws, size_t ws_size,
                              hipStream_t stream) {
  const float* x    = (const float*)d_in[0];
  const float* ln1g = (const float*)d_in[1];
  const float* ln1b = (const float*)d_in[2];
  const float* ln2g = (const float*)d_in[3];
  const float* ln2b = (const float*)d_in[4];
  const float* wq   = (const float*)d_in[5];
  const float* bq   = (const float*)d_in[6];
  const float* wk   = (const float*)d_in[7];
  const float* bk   = (const float*)d_in[8];
  const float* wv   = (const float*)d_in[9];
  const float* bv   = (const float*)d_in[10];
  const float* w1   = (const float*)d_in[11];
  const float* b1   = (const float*)d_in[12];
  const float* w2   = (const float*)d_in[13];
  const float* b2   = (const float*)d_in[14];
  float* outp = (float*)d_out;

  // ---- workspace layout with aliasing (peak ~148 MiB; ws_size is ~256 MiB) ----
  // persistent region: yn, w1t, w2t, wqt, wkt, wvt
  // union region:      { xn, qg, kg, vtb }  (dead after attn)  OVERLAPS  { hbuf }
  char* ws = (char*)d_ws;
  size_t off = 0;
  auto carve = [&](size_t elems) -> short* {
    short* p = (short*)(ws + off);
    off += elems * sizeof(short);
    off = (off + 255) & ~(size_t)255;
    return p;
  };
  short* yn   = carve((size_t)MPAD * DMODEL);
  short* w1t  = carve((size_t)MLPD * DMODEL);
  short* w2t  = carve((size_t)DMODEL * MLPD);
  short* wqt  = carve((size_t)NH * 64 * 64);
  short* wkt  = carve((size_t)NH * 64 * 64);
  short* wvt  = carve((size_t)NH * 64 * 64);
  // union region starts here
  size_t union_base = off;
  short* hbuf = carve((size_t)MPAD * MLPD);           // phase B
  off = union_base;                                    // rewind: phase A aliases
  short* xn   = carve((size_t)NROWS * DMODEL);
  short* qg   = carve((size_t)NBH * S_LEN * DHEAD);
  short* kg   = carve((size_t)NBH * S_LEN * DHEAD);
  short* vtb  = carve((size_t)NBH * DHEAD * SPAD);
  (void)ws_size; (void)in_sizes; (void)n_in; (void)out_size;

  // prep weights
  transpose_w<<<dim3(MLPD / 32, DMODEL / 32), dim3(32, 8), 0, stream>>>(w1, w1t, DMODEL, MLPD);
  transpose_w<<<dim3(DMODEL / 32, MLPD / 32), dim3(32, 8), 0, stream>>>(w2, w2t, MLPD, DMODEL);
  prep_qkv<<<NH, 256, 0, stream>>>(wq, wk, wv, wqt, wkt, wvt);
  pad_vt<<<(NBH * DHEAD * (SPAD - S_LEN) + 255) / 256, 256, 0, stream>>>(vtb);

  // LN1 -> xn (bf16)
  ln_kernel<<<NROWS, 256, 0, stream>>>(x, ln1g, ln1b, xn);

  // QKV projections (V transposed to [bh][d][s])
  qkv_kernel<<<((NROWS + 63) / 64) * NH, 256, 0, stream>>>(xn, wqt, wkt, wvt, bq, bk, bv, qg, kg, vtb);

  // attention + residual1 -> d_out
  attn_kernel<<<dim3(10, NBH), 256, 0, stream>>>(qg, kg, vtb, x, outp);

  // LN2 -> yn  (xn/qg/kg/vtb now dead; hbuf may overwrite them)
  ln_kernel<<<NROWS, 256, 0, stream>>>(outp, ln2g, ln2b, yn);

  // MLP
  gemm_gelu<<<dim3(MPAD / 128, MLPD / 128), 256, 0, stream>>>(yn, w1t, b1, hbuf, MPAD, MLPD, DMODEL);
  gemm_res<<<dim3(MPAD / 128, DMODEL / 128), 256, 0, stream>>>(hbuf, w2t, b2, outp, NROWS, DMODEL, MLPD);
}

// Round 4
// 621.487 us; speedup vs baseline: 1.3087x; 1.1673x over previous
//
#include <hip/hip_runtime.h>

#define S_LEN 577
#define SPAD  640
#define DMODEL 768
#define NH 12
#define DHEAD 64
#define MLPD 3072
#define NROWS (32 * 577)      // 18464
#define MPAD  18560           // 145*128
#define NBH   (32 * 12)       // 384
#define LOG2E 1.44269504088896340736f

typedef __attribute__((ext_vector_type(8))) short s8v;
typedef __attribute__((ext_vector_type(4))) float f4v;

#define MFMA16(a, b, c) __builtin_amdgcn_mfma_f32_16x16x32_bf16((a), (b), (c), 0, 0, 0)

__device__ __forceinline__ short f2bf(float f) {
  union { float f; unsigned u; } a; a.f = f;
  unsigned r = a.u + 0x7FFFu + ((a.u >> 16) & 1u);
  return (short)(r >> 16);
}

__device__ __forceinline__ void gload16(const short* g, const short* l) {
  __builtin_amdgcn_global_load_lds(
      (const __attribute__((address_space(1))) void*)g,
      (__attribute__((address_space(3))) void*)l, 16, 0, 0);
}

// ---------------- prep: transpose fp32 (R,C) -> bf16 (C,R) ----------------
__global__ __launch_bounds__(256) void transpose_w(const float* __restrict__ in,
                                                   short* __restrict__ out, int R, int C) {
  __shared__ float tile[32][33];
  int c0 = blockIdx.x * 32, r0 = blockIdx.y * 32;
  int tx = threadIdx.x, ty = threadIdx.y;
  for (int i = ty; i < 32; i += 8) tile[i][tx] = in[(size_t)(r0 + i) * C + c0 + tx];
  __syncthreads();
  for (int i = ty; i < 32; i += 8) out[(size_t)(c0 + i) * R + r0 + tx] = f2bf(tile[tx][i]);
}

// ---------------- prep: per-head (d,o) -> bf16 (o,d) for wq/wk/wv ----------------
__global__ __launch_bounds__(256) void prep_qkv(const float* __restrict__ wq, const float* __restrict__ wk,
                                                const float* __restrict__ wv, short* __restrict__ oq,
                                                short* __restrict__ ok, short* __restrict__ ov) {
  int h = blockIdx.x, t = threadIdx.x;
  const float* src0 = wq + (size_t)h * 4096;
  const float* src1 = wk + (size_t)h * 4096;
  const float* src2 = wv + (size_t)h * 4096;
  short* dst0 = oq + (size_t)h * 4096;
  short* dst1 = ok + (size_t)h * 4096;
  short* dst2 = ov + (size_t)h * 4096;
  for (int i = t; i < 4096; i += 256) {
    int o = i >> 6, d = i & 63;
    dst0[i] = f2bf(src0[d * 64 + o]);
    dst1[i] = f2bf(src1[d * 64 + o]);
    dst2[i] = f2bf(src2[d * 64 + o]);
  }
}

// ---------------- zero the s-padding of vt: [NBH][64][SPAD], s in [577,640) ----------------
__global__ __launch_bounds__(256) void pad_vt(short* __restrict__ vt) {
  int idx = blockIdx.x * 256 + threadIdx.x;
  const int padw = SPAD - S_LEN;          // 63
  const int per = DHEAD * padw;           // 4032
  if (idx >= NBH * per) return;
  int bh = idx / per, r = idx - bh * per;
  int col = r / padw, s = S_LEN + (r - col * padw);
  vt[((size_t)bh * DHEAD + col) * SPAD + s] = 0;
}

// ---------------- LayerNorm (D=768), fp32 in -> bf16 out ----------------
__global__ __launch_bounds__(256) void ln_kernel(const float* __restrict__ x, const float* __restrict__ g,
                                                 const float* __restrict__ bta, short* __restrict__ out) {
  int row = blockIdx.x;
  int t = threadIdx.x;
  const float* xr = x + (size_t)row * DMODEL;
  float v0 = xr[t], v1 = xr[t + 256], v2 = xr[t + 512];
  float s = v0 + v1 + v2;
  float s2 = v0 * v0 + v1 * v1 + v2 * v2;
  for (int o = 32; o; o >>= 1) { s += __shfl_down(s, o); s2 += __shfl_down(s2, o); }
  __shared__ float red[8];
  if ((t & 63) == 0) { int w = t >> 6; red[w] = s; red[4 + w] = s2; }
  __syncthreads();
  s = red[0] + red[1] + red[2] + red[3];
  s2 = red[4] + red[5] + red[6] + red[7];
  float m = s * (1.f / DMODEL);
  float rs = rsqrtf(s2 * (1.f / DMODEL) - m * m + 1e-5f);
  short* orow = out + (size_t)row * DMODEL;
  orow[t]       = f2bf((v0 - m) * rs * g[t]       + bta[t]);
  orow[t + 256] = f2bf((v1 - m) * rs * g[t + 256] + bta[t + 256]);
  orow[t + 512] = f2bf((v2 - m) * rs * g[t + 512] + bta[t + 512]);
}

// ---------------- QKV: per-head 64x64 GEMM, bias; q pre-scaled (1/8)*log2e; V transposed ----------------
__global__ __launch_bounds__(256) void qkv_kernel(const short* __restrict__ xn,
    const short* __restrict__ wqt, const short* __restrict__ wkt, const short* __restrict__ wvt,
    const float* __restrict__ bq, const float* __restrict__ bk, const float* __restrict__ bv,
    short* __restrict__ qg, short* __restrict__ kg, short* __restrict__ vt) {
  __shared__ __align__(16) short wl[3][64][72];
  int bid = blockIdx.x;
  int h = bid % NH, mt = bid / NH;
  int t = threadIdx.x;
  {
    int o = t >> 2, d0 = (t & 3) * 16;
    const short* s0 = wqt + (size_t)h * 4096 + o * 64 + d0;
    const short* s1 = wkt + (size_t)h * 4096 + o * 64 + d0;
    const short* s2 = wvt + (size_t)h * 4096 + o * 64 + d0;
    *(uint4*)&wl[0][o][d0]     = *(const uint4*)s0;
    *(uint4*)&wl[0][o][d0 + 8] = *(const uint4*)(s0 + 8);
    *(uint4*)&wl[1][o][d0]     = *(const uint4*)s1;
    *(uint4*)&wl[1][o][d0 + 8] = *(const uint4*)(s1 + 8);
    *(uint4*)&wl[2][o][d0]     = *(const uint4*)s2;
    *(uint4*)&wl[2][o][d0 + 8] = *(const uint4*)(s2 + 8);
  }
  __syncthreads();
  int w = t >> 6, l = t & 63, l15 = l & 15, lh = l >> 4;
  int m0 = mt * 64 + w * 16;
  if (m0 >= NROWS) return;
  f4v z = {0.f, 0.f, 0.f, 0.f};
  f4v aq[4], ak[4], av[4];
#pragma unroll
  for (int nt = 0; nt < 4; ++nt) { aq[nt] = z; ak[nt] = z; av[nt] = z; }
  const short* xrow = xn + (size_t)(m0 + l15) * DMODEL + h * DHEAD;
#pragma unroll
  for (int kk = 0; kk < 64; kk += 32) {
    s8v af = *(const s8v*)(xrow + kk + lh * 8);
#pragma unroll
    for (int nt = 0; nt < 4; ++nt) {
      s8v b0 = *(const s8v*)&wl[0][nt * 16 + l15][kk + lh * 8];
      s8v b1 = *(const s8v*)&wl[1][nt * 16 + l15][kk + lh * 8];
      s8v b2 = *(const s8v*)&wl[2][nt * 16 + l15][kk + lh * 8];
      aq[nt] = MFMA16(af, b0, aq[nt]);
      ak[nt] = MFMA16(af, b1, ak[nt]);
      av[nt] = MFMA16(af, b2, av[nt]);
    }
  }
#pragma unroll
  for (int nt = 0; nt < 4; ++nt) {
    int col = nt * 16 + l15;
    float biq = bq[h * DHEAD + col], bik = bk[h * DHEAD + col], biv = bv[h * DHEAD + col];
#pragma unroll
    for (int i = 0; i < 4; ++i) {
      int m = m0 + lh * 4 + i;
      int bb = m / S_LEN;
      int ss = m - bb * S_LEN;
      int bh = bb * NH + h;
      size_t ob = ((size_t)bh * S_LEN + ss) * DHEAD + col;
      qg[ob] = f2bf((aq[nt][i] + biq) * (0.125f * LOG2E));
      kg[ob] = f2bf(ak[nt][i] + bik);
      vt[((size_t)bh * DHEAD + col) * SPAD + ss] = f2bf(av[nt][i] + biv);
    }
  }
}

// ---------------- attention: flash-style, 32 q-rows/wave, K-reg prefetch, exp2 softmax ----------------
__global__ __launch_bounds__(256) void attn_kernel(const short* __restrict__ qg, const short* __restrict__ kg,
                                                   const short* __restrict__ vt, const float* __restrict__ x,
                                                   float* __restrict__ outp) {
  __shared__ __align__(16) short Pb[4][32][72];
  int bh = blockIdx.x;       // 0..383  (x-fastest: same bh's q-tiles separated by 384 in dispatch)
  int qt = blockIdx.y;       // 0..4
  int h = bh % NH, b = bh / NH;
  int t = threadIdx.x, w = t >> 6, l = t & 63, l15 = l & 15, lh = l >> 4;
  int q0 = qt * 128 + w * 32;
  if (q0 > 576) return;
  size_t base  = (size_t)bh * S_LEN * DHEAD;
  size_t vbase = (size_t)bh * DHEAD * SPAD;
  s8v aq[2][2];
#pragma unroll
  for (int f = 0; f < 2; ++f) {
    int qrow = q0 + f * 16 + l15; if (qrow > 576) qrow = 576;
    const short* qp = qg + base + (size_t)qrow * DHEAD + lh * 8;
    aq[f][0] = *(const s8v*)qp;
    aq[f][1] = *(const s8v*)(qp + 32);
  }
  f4v z = {0.f, 0.f, 0.f, 0.f};
  f4v acc[2][4];
  float mrow[2][4], lrow[2][4];
#pragma unroll
  for (int f = 0; f < 2; ++f) {
#pragma unroll
    for (int dt = 0; dt < 4; ++dt) acc[f][dt] = z;
#pragma unroll
    for (int i = 0; i < 4; ++i) { mrow[f][i] = -1e30f; lrow[f][i] = 0.f; }
  }

#define LOADK(KB, K0, K1)                                              \
  {                                                                    \
    _Pragma("unroll")                                                  \
    for (int nt = 0; nt < 4; ++nt) {                                   \
      int key = (KB) + nt * 16 + l15; if (key > 576) key = 576;        \
      const short* kp = kg + base + (size_t)key * DHEAD + lh * 8;      \
      K0[nt] = *(const s8v*)kp;                                        \
      K1[nt] = *(const s8v*)(kp + 32);                                 \
    }                                                                  \
  }

  s8v kf0[4], kf1[4];
  LOADK(0, kf0, kf1);

  for (int kt = 0; kt < 10; ++kt) {
    int kb = kt * 64;
    // ---- QK^T: S[32 q][64 k] ----
    f4v sc[2][4];
#pragma unroll
    for (int nt = 0; nt < 4; ++nt) {
#pragma unroll
      for (int f = 0; f < 2; ++f) {
        f4v a = z;
        a = MFMA16(aq[f][0], kf0[nt], a);
        a = MFMA16(aq[f][1], kf1[nt], a);
        sc[f][nt] = a;
      }
    }
    // ---- prefetch next K tile (latency hidden under softmax VALU) ----
    s8v kn0[4], kn1[4];
    if (kt < 9) LOADK(kb + 64, kn0, kn1);
    if (kt == 9) {
#pragma unroll
      for (int nt = 0; nt < 4; ++nt) {
        int col = kb + nt * 16 + l15;
        if (col > 576) {
#pragma unroll
          for (int f = 0; f < 2; ++f) { sc[f][nt][0] = sc[f][nt][1] = sc[f][nt][2] = sc[f][nt][3] = -1e30f; }
        }
      }
    }
    // ---- online softmax (scores already in log2 units) ----
#pragma unroll
    for (int f = 0; f < 2; ++f) {
#pragma unroll
      for (int i = 0; i < 4; ++i) {
        float m2 = fmaxf(fmaxf(sc[f][0][i], sc[f][1][i]), fmaxf(sc[f][2][i], sc[f][3][i]));
        m2 = fmaxf(m2, __shfl_xor(m2, 1));
        m2 = fmaxf(m2, __shfl_xor(m2, 2));
        m2 = fmaxf(m2, __shfl_xor(m2, 4));
        m2 = fmaxf(m2, __shfl_xor(m2, 8));
        float mn = fmaxf(mrow[f][i], m2);
        float sf = exp2f(mrow[f][i] - mn);
        mrow[f][i] = mn;
        float sum = 0.f;
#pragma unroll
        for (int nt = 0; nt < 4; ++nt) {
          float e = exp2f(sc[f][nt][i] - mn);
          sum += e;
          Pb[w][f * 16 + lh * 4 + i][nt * 16 + l15] = f2bf(e);
        }
        sum += __shfl_xor(sum, 1);
        sum += __shfl_xor(sum, 2);
        sum += __shfl_xor(sum, 4);
        sum += __shfl_xor(sum, 8);
        lrow[f][i] = lrow[f][i] * sf + sum;
#pragma unroll
        for (int dt = 0; dt < 4; ++dt) acc[f][dt][i] *= sf;
      }
    }
    // ---- PV: O += P @ V (V frags shared by both q-frags) ----
#pragma unroll
    for (int kk2 = 0; kk2 < 2; ++kk2) {
      const short* vp = vt + vbase + kb + kk2 * 32 + lh * 8;
      s8v af0 = *(const s8v*)&Pb[w][l15][kk2 * 32 + lh * 8];
      s8v af1 = *(const s8v*)&Pb[w][16 + l15][kk2 * 32 + lh * 8];
#pragma unroll
      for (int dt = 0; dt < 4; ++dt) {
        s8v bf = *(const s8v*)(vp + (size_t)(dt * 16 + l15) * SPAD);
        acc[0][dt] = MFMA16(af0, bf, acc[0][dt]);
        acc[1][dt] = MFMA16(af1, bf, acc[1][dt]);
      }
    }
#pragma unroll
    for (int nt = 0; nt < 4; ++nt) { kf0[nt] = kn0[nt]; kf1[nt] = kn1[nt]; }
  }
#undef LOADK
  // ---- epilogue: normalize + residual ----
#pragma unroll
  for (int f = 0; f < 2; ++f)
#pragma unroll
    for (int i = 0; i < 4; ++i) {
      int srow = q0 + f * 16 + lh * 4 + i;
      if (srow > 576) continue;
      float inv = 1.f / lrow[f][i];
      size_t idx0 = ((size_t)b * S_LEN + srow) * DMODEL + h * DHEAD + l15;
#pragma unroll
      for (int dt = 0; dt < 4; ++dt) {
        size_t idx = idx0 + dt * 16;
        outp[idx] = x[idx] + acc[f][dt][i] * inv;
      }
    }
}

// ================= 128x128 GEMM, double-buffered single-barrier pipeline =================
#define GEMM_STAGE(D, K0)                                                        \
  {                                                                              \
    _Pragma("unroll")                                                            \
    for (int c = 0; c < 4; ++c) {                                                \
      int ch = w * 4 + c;                                                        \
      int row = ch * 8 + lrow;                                                   \
      gload16(A  + (size_t)(m0 + row) * K + (K0) + lcol, &sA[D][0][0] + ch * 512); \
      gload16(Bt + (size_t)(n0 + row) * K + (K0) + lcol, &sB[D][0][0] + ch * 512); \
    }                                                                            \
  }

#define GEMM_COMPUTE(D)                                                          \
  {                                                                              \
    _Pragma("unroll")                                                            \
    for (int kk = 0; kk < 64; kk += 32) {                                        \
      s8v af[4], bf[4];                                                          \
      _Pragma("unroll")                                                          \
      for (int mt = 0; mt < 4; ++mt) af[mt] = *(const s8v*)&sA[D][wr * 64 + mt * 16 + l15][kk + lh * 8]; \
      _Pragma("unroll")                                                          \
      for (int nt = 0; nt < 4; ++nt) bf[nt] = *(const s8v*)&sB[D][wc * 64 + nt * 16 + l15][kk + lh * 8]; \
      _Pragma("unroll")                                                          \
      for (int mt = 0; mt < 4; ++mt)                                             \
        _Pragma("unroll")                                                        \
        for (int nt = 0; nt < 4; ++nt) acc[mt][nt] = MFMA16(af[mt], bf[nt], acc[mt][nt]); \
    }                                                                            \
  }

// ---------------- GEMM + bias + erf-GELU -> bf16 ----------------
__global__ __launch_bounds__(256) void gemm_gelu(const short* __restrict__ A, const short* __restrict__ Bt,
                                                 const float* __restrict__ bias, short* __restrict__ C,
                                                 int M, int N, int K) {
  __shared__ __align__(16) short sA[2][128][64];
  __shared__ __align__(16) short sB[2][128][64];
  int m0 = blockIdx.x * 128, n0 = blockIdx.y * 128;
  int t = threadIdx.x;
  int w = t >> 6, l = t & 63, l15 = l & 15, lh = l >> 4;
  int wr = w >> 1, wc = w & 1;
  int lrow = l >> 3, lcol = (l & 7) * 8;
  f4v z = {0.f, 0.f, 0.f, 0.f};
  f4v acc[4][4];
#pragma unroll
  for (int i = 0; i < 4; ++i)
#pragma unroll
    for (int j = 0; j < 4; ++j) acc[i][j] = z;
  int nsteps = K >> 6;
  GEMM_STAGE(0, 0);
  __syncthreads();
  int cur = 0;
  for (int ts = 0; ts < nsteps; ++ts) {
    if (ts + 1 < nsteps) GEMM_STAGE(cur ^ 1, (ts + 1) * 64);
    GEMM_COMPUTE(cur);
    __syncthreads();
    cur ^= 1;
  }
#pragma unroll
  for (int mt = 0; mt < 4; ++mt)
#pragma unroll
    for (int nt = 0; nt < 4; ++nt) {
      int col = n0 + wc * 64 + nt * 16 + l15;
      float bi = bias[col];
#pragma unroll
      for (int i = 0; i < 4; ++i) {
        int row = m0 + wr * 64 + mt * 16 + lh * 4 + i;
        float v = acc[mt][nt][i] + bi;
        v = 0.5f * v * (1.f + erff(v * 0.70710678118654752f));
        C[(size_t)row * N + col] = f2bf(v);
      }
    }
}

// ---------------- GEMM + bias + residual (in-place on out) ----------------
__global__ __launch_bounds__(256) void gemm_res(const short* __restrict__ A, const short* __restrict__ Bt,
                                                const float* __restrict__ bias, float* __restrict__ outp,
                                                int Mvalid, int N, int K) {
  __shared__ __align__(16) short sA[2][128][64];
  __shared__ __align__(16) short sB[2][128][64];
  int m0 = blockIdx.x * 128, n0 = blockIdx.y * 128;
  int t = threadIdx.x;
  int w = t >> 6, l = t & 63, l15 = l & 15, lh = l >> 4;
  int wr = w >> 1, wc = w & 1;
  int lrow = l >> 3, lcol = (l & 7) * 8;
  f4v z = {0.f, 0.f, 0.f, 0.f};
  f4v acc[4][4];
#pragma unroll
  for (int i = 0; i < 4; ++i)
#pragma unroll
    for (int j = 0; j < 4; ++j) acc[i][j] = z;
  int nsteps = K >> 6;
  GEMM_STAGE(0, 0);
  __syncthreads();
  int cur = 0;
  for (int ts = 0; ts < nsteps; ++ts) {
    if (ts + 1 < nsteps) GEMM_STAGE(cur ^ 1, (ts + 1) * 64);
    GEMM_COMPUTE(cur);
    __syncthreads();
    cur ^= 1;
  }
#pragma unroll
  for (int mt = 0; mt < 4; ++mt)
#pragma unroll
    for (int nt = 0; nt < 4; ++nt) {
      int col = n0 + wc * 64 + nt * 16 + l15;
      float bi = bias[col];
#pragma unroll
      for (int i = 0; i < 4; ++i) {
        int row = m0 + wr * 64 + mt * 16 + lh * 4 + i;
        if (row < Mvalid) {
          size_t idx = (size_t)row * N + col;
          outp[idx] += acc[mt][nt][i] + bi;
        }
      }
    }
}

extern "C" void kernel_launch(void* const* d_in, const int* in_sizes, int n_in,
                              void* d_out, int out_size, void* d_ws, size_t ws_size,
                              hipStream_t stream) {
  const float* x    = (const float*)d_in[0];
  const float* ln1g = (const float*)d_in[1];
  const float* ln1b = (const float*)d_in[2];
  const float* ln2g = (const float*)d_in[3];
  const float* ln2b = (const float*)d_in[4];
  const float* wq   = (const float*)d_in[5];
  const float* bq   = (const float*)d_in[6];
  const float* wk   = (const float*)d_in[7];
  const float* bk   = (const float*)d_in[8];
  const float* wv   = (const float*)d_in[9];
  const float* bv   = (const float*)d_in[10];
  const float* w1   = (const float*)d_in[11];
  const float* b1   = (const float*)d_in[12];
  const float* w2   = (const float*)d_in[13];
  const float* b2   = (const float*)d_in[14];
  float* outp = (float*)d_out;

  // ---- workspace layout with aliasing (peak ~148 MiB) ----
  char* ws = (char*)d_ws;
  size_t off = 0;
  auto carve = [&](size_t elems) -> short* {
    short* p = (short*)(ws + off);
    off += elems * sizeof(short);
    off = (off + 255) & ~(size_t)255;
    return p;
  };
  short* yn   = carve((size_t)MPAD * DMODEL);
  short* w1t  = carve((size_t)MLPD * DMODEL);
  short* w2t  = carve((size_t)DMODEL * MLPD);
  short* wqt  = carve((size_t)NH * 64 * 64);
  short* wkt  = carve((size_t)NH * 64 * 64);
  short* wvt  = carve((size_t)NH * 64 * 64);
  size_t union_base = off;
  short* hbuf = carve((size_t)MPAD * MLPD);           // phase B
  off = union_base;                                    // phase A aliases
  short* xn   = carve((size_t)NROWS * DMODEL);
  short* qg   = carve((size_t)NBH * S_LEN * DHEAD);
  short* kg   = carve((size_t)NBH * S_LEN * DHEAD);
  short* vtb  = carve((size_t)NBH * DHEAD * SPAD);
  (void)ws_size; (void)in_sizes; (void)n_in; (void)out_size;

  // prep weights
  transpose_w<<<dim3(MLPD / 32, DMODEL / 32), dim3(32, 8), 0, stream>>>(w1, w1t, DMODEL, MLPD);
  transpose_w<<<dim3(DMODEL / 32, MLPD / 32), dim3(32, 8), 0, stream>>>(w2, w2t, MLPD, DMODEL);
  prep_qkv<<<NH, 256, 0, stream>>>(wq, wk, wv, wqt, wkt, wvt);
  pad_vt<<<(NBH * DHEAD * (SPAD - S_LEN) + 255) / 256, 256, 0, stream>>>(vtb);

  // LN1 -> xn (bf16)
  ln_kernel<<<NROWS, 256, 0, stream>>>(x, ln1g, ln1b, xn);

  // QKV projections (V transposed to [bh][d][s])
  qkv_kernel<<<((NROWS + 63) / 64) * NH, 256, 0, stream>>>(xn, wqt, wkt, wvt, bq, bk, bv, qg, kg, vtb);

  // attention + residual1 -> d_out
  attn_kernel<<<dim3(NBH, 5), 256, 0, stream>>>(qg, kg, vtb, x, outp);

  // LN2 -> yn
  ln_kernel<<<NROWS, 256, 0, stream>>>(outp, ln2g, ln2b, yn);

  // MLP
  gemm_gelu<<<dim3(MPAD / 128, MLPD / 128), 256, 0, stream>>>(yn, w1t, b1, hbuf, MPAD, MLPD, DMODEL);
  gemm_res<<<dim3(MPAD / 128, DMODEL / 128), 256, 0, stream>>>(hbuf, w2t, b2, outp, NROWS, DMODEL, MLPD);
}

// Round 5
// 609.731 us; speedup vs baseline: 1.3340x; 1.0193x over previous
//
#include <hip/hip_runtime.h>

#define S_LEN 577
#define SPAD  640
#define DMODEL 768
#define NH 12
#define DHEAD 64
#define MLPD 3072
#define NROWS (32 * 577)      // 18464
#define MPAD  18560           // 145*128
#define NBH   (32 * 12)       // 384
#define LOG2E 1.44269504088896340736f

typedef __attribute__((ext_vector_type(8))) short s8v;
typedef __attribute__((ext_vector_type(4))) float f4v;

#define MFMA16(a, b, c) __builtin_amdgcn_mfma_f32_16x16x32_bf16((a), (b), (c), 0, 0, 0)

__device__ __forceinline__ short f2bf(float f) {
  union { float f; unsigned u; } a; a.f = f;
  unsigned r = a.u + 0x7FFFu + ((a.u >> 16) & 1u);
  return (short)(r >> 16);
}

__device__ __forceinline__ void gload16(const short* g, const short* l) {
  __builtin_amdgcn_global_load_lds(
      (const __attribute__((address_space(1))) void*)g,
      (__attribute__((address_space(3))) void*)l, 16, 0, 0);
}

// ---------------- prep: transpose fp32 (R,C) -> bf16 (C,R) ----------------
__global__ __launch_bounds__(256) void transpose_w(const float* __restrict__ in,
                                                   short* __restrict__ out, int R, int C) {
  __shared__ float tile[32][33];
  int c0 = blockIdx.x * 32, r0 = blockIdx.y * 32;
  int tx = threadIdx.x, ty = threadIdx.y;
  for (int i = ty; i < 32; i += 8) tile[i][tx] = in[(size_t)(r0 + i) * C + c0 + tx];
  __syncthreads();
  for (int i = ty; i < 32; i += 8) out[(size_t)(c0 + i) * R + r0 + tx] = f2bf(tile[tx][i]);
}

// ---------------- prep: per-head (d,o) -> bf16 (o,d) for wq/wk/wv ----------------
__global__ __launch_bounds__(256) void prep_qkv(const float* __restrict__ wq, const float* __restrict__ wk,
                                                const float* __restrict__ wv, short* __restrict__ oq,
                                                short* __restrict__ ok, short* __restrict__ ov) {
  int h = blockIdx.x, t = threadIdx.x;
  const float* src0 = wq + (size_t)h * 4096;
  const float* src1 = wk + (size_t)h * 4096;
  const float* src2 = wv + (size_t)h * 4096;
  short* dst0 = oq + (size_t)h * 4096;
  short* dst1 = ok + (size_t)h * 4096;
  short* dst2 = ov + (size_t)h * 4096;
  for (int i = t; i < 4096; i += 256) {
    int o = i >> 6, d = i & 63;
    dst0[i] = f2bf(src0[d * 64 + o]);
    dst1[i] = f2bf(src1[d * 64 + o]);
    dst2[i] = f2bf(src2[d * 64 + o]);
  }
}

// ---------------- zero the s-padding of vt: [NBH][64][SPAD], s in [577,640) ----------------
__global__ __launch_bounds__(256) void pad_vt(short* __restrict__ vt) {
  int idx = blockIdx.x * 256 + threadIdx.x;
  const int padw = SPAD - S_LEN;          // 63
  const int per = DHEAD * padw;           // 4032
  if (idx >= NBH * per) return;
  int bh = idx / per, r = idx - bh * per;
  int col = r / padw, s = S_LEN + (r - col * padw);
  vt[((size_t)bh * DHEAD + col) * SPAD + s] = 0;
}

// ---------------- LayerNorm (D=768), fp32 in -> bf16 out ----------------
__global__ __launch_bounds__(256) void ln_kernel(const float* __restrict__ x, const float* __restrict__ g,
                                                 const float* __restrict__ bta, short* __restrict__ out) {
  int row = blockIdx.x;
  int t = threadIdx.x;
  const float* xr = x + (size_t)row * DMODEL;
  float v0 = xr[t], v1 = xr[t + 256], v2 = xr[t + 512];
  float s = v0 + v1 + v2;
  float s2 = v0 * v0 + v1 * v1 + v2 * v2;
  for (int o = 32; o; o >>= 1) { s += __shfl_down(s, o); s2 += __shfl_down(s2, o); }
  __shared__ float red[8];
  if ((t & 63) == 0) { int w = t >> 6; red[w] = s; red[4 + w] = s2; }
  __syncthreads();
  s = red[0] + red[1] + red[2] + red[3];
  s2 = red[4] + red[5] + red[6] + red[7];
  float m = s * (1.f / DMODEL);
  float rs = rsqrtf(s2 * (1.f / DMODEL) - m * m + 1e-5f);
  short* orow = out + (size_t)row * DMODEL;
  orow[t]       = f2bf((v0 - m) * rs * g[t]       + bta[t]);
  orow[t + 256] = f2bf((v1 - m) * rs * g[t + 256] + bta[t + 256]);
  orow[t + 512] = f2bf((v2 - m) * rs * g[t + 512] + bta[t + 512]);
}

// ---------------- QKV: per-head 64x64 GEMM, bias; q pre-scaled (1/8)*log2e; V transposed ----------------
__global__ __launch_bounds__(256) void qkv_kernel(const short* __restrict__ xn,
    const short* __restrict__ wqt, const short* __restrict__ wkt, const short* __restrict__ wvt,
    const float* __restrict__ bq, const float* __restrict__ bk, const float* __restrict__ bv,
    short* __restrict__ qg, short* __restrict__ kg, short* __restrict__ vt) {
  __shared__ __align__(16) short wl[3][64][72];
  int bid = blockIdx.x;
  int h = bid % NH, mt = bid / NH;
  int t = threadIdx.x;
  {
    int o = t >> 2, d0 = (t & 3) * 16;
    const short* s0 = wqt + (size_t)h * 4096 + o * 64 + d0;
    const short* s1 = wkt + (size_t)h * 4096 + o * 64 + d0;
    const short* s2 = wvt + (size_t)h * 4096 + o * 64 + d0;
    *(uint4*)&wl[0][o][d0]     = *(const uint4*)s0;
    *(uint4*)&wl[0][o][d0 + 8] = *(const uint4*)(s0 + 8);
    *(uint4*)&wl[1][o][d0]     = *(const uint4*)s1;
    *(uint4*)&wl[1][o][d0 + 8] = *(const uint4*)(s1 + 8);
    *(uint4*)&wl[2][o][d0]     = *(const uint4*)s2;
    *(uint4*)&wl[2][o][d0 + 8] = *(const uint4*)(s2 + 8);
  }
  __syncthreads();
  int w = t >> 6, l = t & 63, l15 = l & 15, lh = l >> 4;
  int m0 = mt * 64 + w * 16;
  if (m0 >= NROWS) return;
  f4v z = {0.f, 0.f, 0.f, 0.f};
  f4v aq[4], ak[4], av[4];
#pragma unroll
  for (int nt = 0; nt < 4; ++nt) { aq[nt] = z; ak[nt] = z; av[nt] = z; }
  const short* xrow = xn + (size_t)(m0 + l15) * DMODEL + h * DHEAD;
#pragma unroll
  for (int kk = 0; kk < 64; kk += 32) {
    s8v af = *(const s8v*)(xrow + kk + lh * 8);
#pragma unroll
    for (int nt = 0; nt < 4; ++nt) {
      s8v b0 = *(const s8v*)&wl[0][nt * 16 + l15][kk + lh * 8];
      s8v b1 = *(const s8v*)&wl[1][nt * 16 + l15][kk + lh * 8];
      s8v b2 = *(const s8v*)&wl[2][nt * 16 + l15][kk + lh * 8];
      aq[nt] = MFMA16(af, b0, aq[nt]);
      ak[nt] = MFMA16(af, b1, ak[nt]);
      av[nt] = MFMA16(af, b2, av[nt]);
    }
  }
#pragma unroll
  for (int nt = 0; nt < 4; ++nt) {
    int col = nt * 16 + l15;
    float biq = bq[h * DHEAD + col], bik = bk[h * DHEAD + col], biv = bv[h * DHEAD + col];
#pragma unroll
    for (int i = 0; i < 4; ++i) {
      int m = m0 + lh * 4 + i;
      int bb = m / S_LEN;
      int ss = m - bb * S_LEN;
      int bh = bb * NH + h;
      size_t ob = ((size_t)bh * S_LEN + ss) * DHEAD + col;
      qg[ob] = f2bf((aq[nt][i] + biq) * (0.125f * LOG2E));
      kg[ob] = f2bf(ak[nt][i] + bik);
      vt[((size_t)bh * DHEAD + col) * SPAD + ss] = f2bf(av[nt][i] + biv);
    }
  }
}

// ---------------- attention: flash-style, 32 q-rows/wave, K-reg prefetch, exp2 softmax ----------------
__global__ __launch_bounds__(256) void attn_kernel(const short* __restrict__ qg, const short* __restrict__ kg,
                                                   const short* __restrict__ vt, const float* __restrict__ x,
                                                   float* __restrict__ outp) {
  __shared__ __align__(16) short Pb[4][32][72];
  int bh = blockIdx.x;       // 0..383
  int qt = blockIdx.y;       // 0..4
  int h = bh % NH, b = bh / NH;
  int t = threadIdx.x, w = t >> 6, l = t & 63, l15 = l & 15, lh = l >> 4;
  int q0 = qt * 128 + w * 32;
  if (q0 > 576) return;
  size_t base  = (size_t)bh * S_LEN * DHEAD;
  size_t vbase = (size_t)bh * DHEAD * SPAD;
  s8v aq[2][2];
#pragma unroll
  for (int f = 0; f < 2; ++f) {
    int qrow = q0 + f * 16 + l15; if (qrow > 576) qrow = 576;
    const short* qp = qg + base + (size_t)qrow * DHEAD + lh * 8;
    aq[f][0] = *(const s8v*)qp;
    aq[f][1] = *(const s8v*)(qp + 32);
  }
  f4v z = {0.f, 0.f, 0.f, 0.f};
  f4v acc[2][4];
  float mrow[2][4], lrow[2][4];
#pragma unroll
  for (int f = 0; f < 2; ++f) {
#pragma unroll
    for (int dt = 0; dt < 4; ++dt) acc[f][dt] = z;
#pragma unroll
    for (int i = 0; i < 4; ++i) { mrow[f][i] = -1e30f; lrow[f][i] = 0.f; }
  }

#define LOADK(KB, K0, K1)                                              \
  {                                                                    \
    _Pragma("unroll")                                                  \
    for (int nt = 0; nt < 4; ++nt) {                                   \
      int key = (KB) + nt * 16 + l15; if (key > 576) key = 576;        \
      const short* kp = kg + base + (size_t)key * DHEAD + lh * 8;      \
      K0[nt] = *(const s8v*)kp;                                        \
      K1[nt] = *(const s8v*)(kp + 32);                                 \
    }                                                                  \
  }

  s8v kf0[4], kf1[4];
  LOADK(0, kf0, kf1);

  for (int kt = 0; kt < 10; ++kt) {
    int kb = kt * 64;
    f4v sc[2][4];
#pragma unroll
    for (int nt = 0; nt < 4; ++nt) {
#pragma unroll
      for (int f = 0; f < 2; ++f) {
        f4v a = z;
        a = MFMA16(aq[f][0], kf0[nt], a);
        a = MFMA16(aq[f][1], kf1[nt], a);
        sc[f][nt] = a;
      }
    }
    s8v kn0[4], kn1[4];
    if (kt < 9) LOADK(kb + 64, kn0, kn1);
    if (kt == 9) {
#pragma unroll
      for (int nt = 0; nt < 4; ++nt) {
        int col = kb + nt * 16 + l15;
        if (col > 576) {
#pragma unroll
          for (int f = 0; f < 2; ++f) { sc[f][nt][0] = sc[f][nt][1] = sc[f][nt][2] = sc[f][nt][3] = -1e30f; }
        }
      }
    }
#pragma unroll
    for (int f = 0; f < 2; ++f) {
#pragma unroll
      for (int i = 0; i < 4; ++i) {
        float m2 = fmaxf(fmaxf(sc[f][0][i], sc[f][1][i]), fmaxf(sc[f][2][i], sc[f][3][i]));
        m2 = fmaxf(m2, __shfl_xor(m2, 1));
        m2 = fmaxf(m2, __shfl_xor(m2, 2));
        m2 = fmaxf(m2, __shfl_xor(m2, 4));
        m2 = fmaxf(m2, __shfl_xor(m2, 8));
        float mn = fmaxf(mrow[f][i], m2);
        float sf = exp2f(mrow[f][i] - mn);
        mrow[f][i] = mn;
        float sum = 0.f;
#pragma unroll
        for (int nt = 0; nt < 4; ++nt) {
          float e = exp2f(sc[f][nt][i] - mn);
          sum += e;
          Pb[w][f * 16 + lh * 4 + i][nt * 16 + l15] = f2bf(e);
        }
        sum += __shfl_xor(sum, 1);
        sum += __shfl_xor(sum, 2);
        sum += __shfl_xor(sum, 4);
        sum += __shfl_xor(sum, 8);
        lrow[f][i] = lrow[f][i] * sf + sum;
#pragma unroll
        for (int dt = 0; dt < 4; ++dt) acc[f][dt][i] *= sf;
      }
    }
#pragma unroll
    for (int kk2 = 0; kk2 < 2; ++kk2) {
      const short* vp = vt + vbase + kb + kk2 * 32 + lh * 8;
      s8v af0 = *(const s8v*)&Pb[w][l15][kk2 * 32 + lh * 8];
      s8v af1 = *(const s8v*)&Pb[w][16 + l15][kk2 * 32 + lh * 8];
#pragma unroll
      for (int dt = 0; dt < 4; ++dt) {
        s8v bf = *(const s8v*)(vp + (size_t)(dt * 16 + l15) * SPAD);
        acc[0][dt] = MFMA16(af0, bf, acc[0][dt]);
        acc[1][dt] = MFMA16(af1, bf, acc[1][dt]);
      }
    }
#pragma unroll
    for (int nt = 0; nt < 4; ++nt) { kf0[nt] = kn0[nt]; kf1[nt] = kn1[nt]; }
  }
#undef LOADK
#pragma unroll
  for (int f = 0; f < 2; ++f)
#pragma unroll
    for (int i = 0; i < 4; ++i) {
      int srow = q0 + f * 16 + lh * 4 + i;
      if (srow > 576) continue;
      float inv = 1.f / lrow[f][i];
      size_t idx0 = ((size_t)b * S_LEN + srow) * DMODEL + h * DHEAD + l15;
#pragma unroll
      for (int dt = 0; dt < 4; ++dt) {
        size_t idx = idx0 + dt * 16;
        outp[idx] = x[idx] + acc[f][dt][i] * inv;
      }
    }
}

// ================= 128x128 GEMM, BK=32 double-buffer (32 KB LDS), 1 barrier/step =================
// chunk ch = w*2+c (0..7), 1 KB each; row = ch*16 + l/4, col = (l&3)*8 shorts
#define GEMM_STAGE(D, K0)                                                          \
  {                                                                                \
    _Pragma("unroll")                                                              \
    for (int c = 0; c < 2; ++c) {                                                  \
      int ch = w * 2 + c;                                                          \
      int row = ch * 16 + (l >> 2);                                                \
      int cs = (l & 3) * 8;                                                        \
      gload16(A  + (size_t)(m0 + row) * K + (K0) + cs, &sA[D][0][0] + ch * 512);   \
      gload16(Bt + (size_t)(n0 + row) * K + (K0) + cs, &sB[D][0][0] + ch * 512);   \
    }                                                                              \
  }

#define GEMM_COMPUTE(D)                                                            \
  {                                                                                \
    s8v af[4], bf[4];                                                              \
    _Pragma("unroll")                                                              \
    for (int mt = 0; mt < 4; ++mt) af[mt] = *(const s8v*)&sA[D][wr * 64 + mt * 16 + l15][lh * 8]; \
    _Pragma("unroll")                                                              \
    for (int nt = 0; nt < 4; ++nt) bf[nt] = *(const s8v*)&sB[D][wc * 64 + nt * 16 + l15][lh * 8]; \
    _Pragma("unroll")                                                              \
    for (int mt = 0; mt < 4; ++mt)                                                 \
      _Pragma("unroll")                                                            \
      for (int nt = 0; nt < 4; ++nt) acc[mt][nt] = MFMA16(af[mt], bf[nt], acc[mt][nt]); \
  }

#define GEMM_PROLOGUE                                                              \
  int m0 = blockIdx.x * 128, n0 = blockIdx.y * 128;                                \
  int t = threadIdx.x;                                                             \
  int w = t >> 6, l = t & 63, l15 = l & 15, lh = l >> 4;                           \
  int wr = w >> 1, wc = w & 1;                                                     \
  f4v z = {0.f, 0.f, 0.f, 0.f};                                                    \
  f4v acc[4][4];                                                                   \
  _Pragma("unroll")                                                                \
  for (int i = 0; i < 4; ++i)                                                      \
    _Pragma("unroll")                                                              \
    for (int j = 0; j < 4; ++j) acc[i][j] = z;                                     \
  int nsteps = K >> 5;                                                             \
  GEMM_STAGE(0, 0);                                                                \
  __syncthreads();                                                                 \
  int cur = 0;                                                                     \
  for (int ts = 0; ts < nsteps; ++ts) {                                            \
    if (ts + 1 < nsteps) GEMM_STAGE(cur ^ 1, (ts + 1) * 32);                       \
    GEMM_COMPUTE(cur);                                                             \
    __syncthreads();                                                               \
    cur ^= 1;                                                                      \
  }

// ---------------- GEMM + bias + GELU (sigmoid-form tanh approx) -> bf16 ----------------
__global__ __launch_bounds__(256) void gemm_gelu(const short* __restrict__ A, const short* __restrict__ Bt,
                                                 const float* __restrict__ bias, short* __restrict__ C,
                                                 int M, int N, int K) {
  __shared__ __align__(16) short sA[2][128][32];
  __shared__ __align__(16) short sB[2][128][32];
  GEMM_PROLOGUE
#pragma unroll
  for (int mt = 0; mt < 4; ++mt)
#pragma unroll
    for (int nt = 0; nt < 4; ++nt) {
      int col = n0 + wc * 64 + nt * 16 + l15;
      float bi = bias[col];
#pragma unroll
      for (int i = 0; i < 4; ++i) {
        int row = m0 + wr * 64 + mt * 16 + lh * 4 + i;
        float v = acc[mt][nt][i] + bi;
        // gelu(v) ~= v * sigmoid(1.5957691*(v + 0.044715 v^3)); constants pre-multiplied by log2e
        float u = v * (2.30221838f + 0.10294364f * v * v);
        v = v / (1.f + exp2f(-u));
        C[(size_t)row * N + col] = f2bf(v);
      }
    }
}

// ---------------- GEMM + bias + residual (in-place on out) ----------------
__global__ __launch_bounds__(256) void gemm_res(const short* __restrict__ A, const short* __restrict__ Bt,
                                                const float* __restrict__ bias, float* __restrict__ outp,
                                                int Mvalid, int N, int K) {
  __shared__ __align__(16) short sA[2][128][32];
  __shared__ __align__(16) short sB[2][128][32];
  GEMM_PROLOGUE
#pragma unroll
  for (int mt = 0; mt < 4; ++mt)
#pragma unroll
    for (int nt = 0; nt < 4; ++nt) {
      int col = n0 + wc * 64 + nt * 16 + l15;
      float bi = bias[col];
#pragma unroll
      for (int i = 0; i < 4; ++i) {
        int row = m0 + wr * 64 + mt * 16 + lh * 4 + i;
        if (row < Mvalid) {
          size_t idx = (size_t)row * N + col;
          outp[idx] += acc[mt][nt][i] + bi;
        }
      }
    }
}

extern "C" void kernel_launch(void* const* d_in, const int* in_sizes, int n_in,
                              void* d_out, int out_size, void* d_ws, size_t ws_size,
                              hipStream_t stream) {
  const float* x    = (const float*)d_in[0];
  const float* ln1g = (const float*)d_in[1];
  const float* ln1b = (const float*)d_in[2];
  const float* ln2g = (const float*)d_in[3];
  const float* ln2b = (const float*)d_in[4];
  const float* wq   = (const float*)d_in[5];
  const float* bq   = (const float*)d_in[6];
  const float* wk   = (const float*)d_in[7];
  const float* bk   = (const float*)d_in[8];
  const float* wv   = (const float*)d_in[9];
  const float* bv   = (const float*)d_in[10];
  const float* w1   = (const float*)d_in[11];
  const float* b1   = (const float*)d_in[12];
  const float* w2   = (const float*)d_in[13];
  const float* b2   = (const float*)d_in[14];
  float* outp = (float*)d_out;

  // ---- workspace layout with aliasing (peak ~148 MiB) ----
  char* ws = (char*)d_ws;
  size_t off = 0;
  auto carve = [&](size_t elems) -> short* {
    short* p = (short*)(ws + off);
    off += elems * sizeof(short);
    off = (off + 255) & ~(size_t)255;
    return p;
  };
  short* yn   = carve((size_t)MPAD * DMODEL);
  short* w1t  = carve((size_t)MLPD * DMODEL);
  short* w2t  = carve((size_t)DMODEL * MLPD);
  short* wqt  = carve((size_t)NH * 64 * 64);
  short* wkt  = carve((size_t)NH * 64 * 64);
  short* wvt  = carve((size_t)NH * 64 * 64);
  size_t union_base = off;
  short* hbuf = carve((size_t)MPAD * MLPD);           // phase B
  off = union_base;                                    // phase A aliases
  short* xn   = carve((size_t)NROWS * DMODEL);
  short* qg   = carve((size_t)NBH * S_LEN * DHEAD);
  short* kg   = carve((size_t)NBH * S_LEN * DHEAD);
  short* vtb  = carve((size_t)NBH * DHEAD * SPAD);
  (void)ws_size; (void)in_sizes; (void)n_in; (void)out_size;

  // prep weights
  transpose_w<<<dim3(MLPD / 32, DMODEL / 32), dim3(32, 8), 0, stream>>>(w1, w1t, DMODEL, MLPD);
  transpose_w<<<dim3(DMODEL / 32, MLPD / 32), dim3(32, 8), 0, stream>>>(w2, w2t, MLPD, DMODEL);
  prep_qkv<<<NH, 256, 0, stream>>>(wq, wk, wv, wqt, wkt, wvt);
  pad_vt<<<(NBH * DHEAD * (SPAD - S_LEN) + 255) / 256, 256, 0, stream>>>(vtb);

  // LN1 -> xn (bf16)
  ln_kernel<<<NROWS, 256, 0, stream>>>(x, ln1g, ln1b, xn);

  // QKV projections (V transposed to [bh][d][s])
  qkv_kernel<<<((NROWS + 63) / 64) * NH, 256, 0, stream>>>(xn, wqt, wkt, wvt, bq, bk, bv, qg, kg, vtb);

  // attention + residual1 -> d_out
  attn_kernel<<<dim3(NBH, 5), 256, 0, stream>>>(qg, kg, vtb, x, outp);

  // LN2 -> yn
  ln_kernel<<<NROWS, 256, 0, stream>>>(outp, ln2g, ln2b, yn);

  // MLP
  gemm_gelu<<<dim3(MPAD / 128, MLPD / 128), 256, 0, stream>>>(yn, w1t, b1, hbuf, MPAD, MLPD, DMODEL);
  gemm_res<<<dim3(MPAD / 128, DMODEL / 128), 256, 0, stream>>>(hbuf, w2t, b2, outp, NROWS, DMODEL, MLPD);
}

// Round 6
// 575.622 us; speedup vs baseline: 1.4130x; 1.0593x over previous
//
#include <hip/hip_runtime.h>

#define S_LEN 577
#define SPAD  640
#define DMODEL 768
#define NH 12
#define DHEAD 64
#define MLPD 3072
#define NROWS (32 * 577)      // 18464
#define MPAD  18560           // 145*128
#define NBH   (32 * 12)       // 384
#define LOG2E 1.44269504088896340736f

typedef __attribute__((ext_vector_type(8))) short s8v;
typedef __attribute__((ext_vector_type(4))) float f4v;

#define MFMA16(a, b, c) __builtin_amdgcn_mfma_f32_16x16x32_bf16((a), (b), (c), 0, 0, 0)

__device__ __forceinline__ short f2bf(float f) {
  union { float f; unsigned u; } a; a.f = f;
  unsigned r = a.u + 0x7FFFu + ((a.u >> 16) & 1u);
  return (short)(r >> 16);
}

__device__ __forceinline__ void gload16(const short* g, const short* l) {
  __builtin_amdgcn_global_load_lds(
      (const __attribute__((address_space(1))) void*)g,
      (__attribute__((address_space(3))) void*)l, 16, 0, 0);
}

// ---------------- prep: transpose fp32 (R,C) -> bf16 (C,R) ----------------
__global__ __launch_bounds__(256) void transpose_w(const float* __restrict__ in,
                                                   short* __restrict__ out, int R, int C) {
  __shared__ float tile[32][33];
  int c0 = blockIdx.x * 32, r0 = blockIdx.y * 32;
  int tx = threadIdx.x, ty = threadIdx.y;
  for (int i = ty; i < 32; i += 8) tile[i][tx] = in[(size_t)(r0 + i) * C + c0 + tx];
  __syncthreads();
  for (int i = ty; i < 32; i += 8) out[(size_t)(c0 + i) * R + r0 + tx] = f2bf(tile[tx][i]);
}

// ---------------- prep: per-head (d,o) -> bf16 (o,d) for wq/wk/wv ----------------
__global__ __launch_bounds__(256) void prep_qkv(const float* __restrict__ wq, const float* __restrict__ wk,
                                                const float* __restrict__ wv, short* __restrict__ oq,
                                                short* __restrict__ ok, short* __restrict__ ov) {
  int h = blockIdx.x, t = threadIdx.x;
  const float* src0 = wq + (size_t)h * 4096;
  const float* src1 = wk + (size_t)h * 4096;
  const float* src2 = wv + (size_t)h * 4096;
  short* dst0 = oq + (size_t)h * 4096;
  short* dst1 = ok + (size_t)h * 4096;
  short* dst2 = ov + (size_t)h * 4096;
  for (int i = t; i < 4096; i += 256) {
    int o = i >> 6, d = i & 63;
    dst0[i] = f2bf(src0[d * 64 + o]);
    dst1[i] = f2bf(src1[d * 64 + o]);
    dst2[i] = f2bf(src2[d * 64 + o]);
  }
}

// ---------------- zero the s-padding of vt: [NBH][64][SPAD], s in [577,640) ----------------
__global__ __launch_bounds__(256) void pad_vt(short* __restrict__ vt) {
  int idx = blockIdx.x * 256 + threadIdx.x;
  const int padw = SPAD - S_LEN;          // 63
  const int per = DHEAD * padw;           // 4032
  if (idx >= NBH * per) return;
  int bh = idx / per, r = idx - bh * per;
  int col = r / padw, s = S_LEN + (r - col * padw);
  vt[((size_t)bh * DHEAD + col) * SPAD + s] = 0;
}

// ---------------- LayerNorm (D=768), fp32 in -> bf16 out ----------------
__global__ __launch_bounds__(256) void ln_kernel(const float* __restrict__ x, const float* __restrict__ g,
                                                 const float* __restrict__ bta, short* __restrict__ out) {
  int row = blockIdx.x;
  int t = threadIdx.x;
  const float* xr = x + (size_t)row * DMODEL;
  float v0 = xr[t], v1 = xr[t + 256], v2 = xr[t + 512];
  float s = v0 + v1 + v2;
  float s2 = v0 * v0 + v1 * v1 + v2 * v2;
  for (int o = 32; o; o >>= 1) { s += __shfl_down(s, o); s2 += __shfl_down(s2, o); }
  __shared__ float red[8];
  if ((t & 63) == 0) { int w = t >> 6; red[w] = s; red[4 + w] = s2; }
  __syncthreads();
  s = red[0] + red[1] + red[2] + red[3];
  s2 = red[4] + red[5] + red[6] + red[7];
  float m = s * (1.f / DMODEL);
  float rs = rsqrtf(s2 * (1.f / DMODEL) - m * m + 1e-5f);
  short* orow = out + (size_t)row * DMODEL;
  orow[t]       = f2bf((v0 - m) * rs * g[t]       + bta[t]);
  orow[t + 256] = f2bf((v1 - m) * rs * g[t + 256] + bta[t + 256]);
  orow[t + 512] = f2bf((v2 - m) * rs * g[t + 512] + bta[t + 512]);
}

// ---------------- QKV: per-head 64x64 GEMM, bias; q pre-scaled (1/8)*log2e; V transposed ----------------
__global__ __launch_bounds__(256) void qkv_kernel(const short* __restrict__ xn,
    const short* __restrict__ wqt, const short* __restrict__ wkt, const short* __restrict__ wvt,
    const float* __restrict__ bq, const float* __restrict__ bk, const float* __restrict__ bv,
    short* __restrict__ qg, short* __restrict__ kg, short* __restrict__ vt) {
  __shared__ __align__(16) short wl[3][64][72];
  int bid = blockIdx.x;
  int h = bid % NH, mt = bid / NH;
  int t = threadIdx.x;
  {
    int o = t >> 2, d0 = (t & 3) * 16;
    const short* s0 = wqt + (size_t)h * 4096 + o * 64 + d0;
    const short* s1 = wkt + (size_t)h * 4096 + o * 64 + d0;
    const short* s2 = wvt + (size_t)h * 4096 + o * 64 + d0;
    *(uint4*)&wl[0][o][d0]     = *(const uint4*)s0;
    *(uint4*)&wl[0][o][d0 + 8] = *(const uint4*)(s0 + 8);
    *(uint4*)&wl[1][o][d0]     = *(const uint4*)s1;
    *(uint4*)&wl[1][o][d0 + 8] = *(const uint4*)(s1 + 8);
    *(uint4*)&wl[2][o][d0]     = *(const uint4*)s2;
    *(uint4*)&wl[2][o][d0 + 8] = *(const uint4*)(s2 + 8);
  }
  __syncthreads();
  int w = t >> 6, l = t & 63, l15 = l & 15, lh = l >> 4;
  int m0 = mt * 64 + w * 16;
  if (m0 >= NROWS) return;
  f4v z = {0.f, 0.f, 0.f, 0.f};
  f4v aq[4], ak[4], av[4];
#pragma unroll
  for (int nt = 0; nt < 4; ++nt) { aq[nt] = z; ak[nt] = z; av[nt] = z; }
  const short* xrow = xn + (size_t)(m0 + l15) * DMODEL + h * DHEAD;
#pragma unroll
  for (int kk = 0; kk < 64; kk += 32) {
    s8v af = *(const s8v*)(xrow + kk + lh * 8);
#pragma unroll
    for (int nt = 0; nt < 4; ++nt) {
      s8v b0 = *(const s8v*)&wl[0][nt * 16 + l15][kk + lh * 8];
      s8v b1 = *(const s8v*)&wl[1][nt * 16 + l15][kk + lh * 8];
      s8v b2 = *(const s8v*)&wl[2][nt * 16 + l15][kk + lh * 8];
      aq[nt] = MFMA16(af, b0, aq[nt]);
      ak[nt] = MFMA16(af, b1, ak[nt]);
      av[nt] = MFMA16(af, b2, av[nt]);
    }
  }
#pragma unroll
  for (int nt = 0; nt < 4; ++nt) {
    int col = nt * 16 + l15;
    float biq = bq[h * DHEAD + col], bik = bk[h * DHEAD + col], biv = bv[h * DHEAD + col];
#pragma unroll
    for (int i = 0; i < 4; ++i) {
      int m = m0 + lh * 4 + i;
      int bb = m / S_LEN;
      int ss = m - bb * S_LEN;
      int bh = bb * NH + h;
      size_t ob = ((size_t)bh * S_LEN + ss) * DHEAD + col;
      qg[ob] = f2bf((aq[nt][i] + biq) * (0.125f * LOG2E));
      kg[ob] = f2bf(ak[nt][i] + bik);
      vt[((size_t)bh * DHEAD + col) * SPAD + ss] = f2bf(av[nt][i] + biv);
    }
  }
}

// ---------------- attention: flash-style, 32 q-rows/wave, K-reg prefetch, exp2 softmax ----------------
__global__ __launch_bounds__(256) void attn_kernel(const short* __restrict__ qg, const short* __restrict__ kg,
                                                   const short* __restrict__ vt, const float* __restrict__ x,
                                                   float* __restrict__ outp) {
  __shared__ __align__(16) short Pb[4][32][72];
  int bh = blockIdx.x;       // 0..383
  int qt = blockIdx.y;       // 0..4
  int h = bh % NH, b = bh / NH;
  int t = threadIdx.x, w = t >> 6, l = t & 63, l15 = l & 15, lh = l >> 4;
  int q0 = qt * 128 + w * 32;
  if (q0 > 576) return;
  size_t base  = (size_t)bh * S_LEN * DHEAD;
  size_t vbase = (size_t)bh * DHEAD * SPAD;
  s8v aq[2][2];
#pragma unroll
  for (int f = 0; f < 2; ++f) {
    int qrow = q0 + f * 16 + l15; if (qrow > 576) qrow = 576;
    const short* qp = qg + base + (size_t)qrow * DHEAD + lh * 8;
    aq[f][0] = *(const s8v*)qp;
    aq[f][1] = *(const s8v*)(qp + 32);
  }
  f4v z = {0.f, 0.f, 0.f, 0.f};
  f4v acc[2][4];
  float mrow[2][4], lrow[2][4];
#pragma unroll
  for (int f = 0; f < 2; ++f) {
#pragma unroll
    for (int dt = 0; dt < 4; ++dt) acc[f][dt] = z;
#pragma unroll
    for (int i = 0; i < 4; ++i) { mrow[f][i] = -1e30f; lrow[f][i] = 0.f; }
  }

#define LOADK(KB, K0, K1)                                              \
  {                                                                    \
    _Pragma("unroll")                                                  \
    for (int nt = 0; nt < 4; ++nt) {                                   \
      int key = (KB) + nt * 16 + l15; if (key > 576) key = 576;        \
      const short* kp = kg + base + (size_t)key * DHEAD + lh * 8;      \
      K0[nt] = *(const s8v*)kp;                                        \
      K1[nt] = *(const s8v*)(kp + 32);                                 \
    }                                                                  \
  }

  s8v kf0[4], kf1[4];
  LOADK(0, kf0, kf1);

  for (int kt = 0; kt < 10; ++kt) {
    int kb = kt * 64;
    f4v sc[2][4];
#pragma unroll
    for (int nt = 0; nt < 4; ++nt) {
#pragma unroll
      for (int f = 0; f < 2; ++f) {
        f4v a = z;
        a = MFMA16(aq[f][0], kf0[nt], a);
        a = MFMA16(aq[f][1], kf1[nt], a);
        sc[f][nt] = a;
      }
    }
    s8v kn0[4], kn1[4];
    if (kt < 9) LOADK(kb + 64, kn0, kn1);
    if (kt == 9) {
#pragma unroll
      for (int nt = 0; nt < 4; ++nt) {
        int col = kb + nt * 16 + l15;
        if (col > 576) {
#pragma unroll
          for (int f = 0; f < 2; ++f) { sc[f][nt][0] = sc[f][nt][1] = sc[f][nt][2] = sc[f][nt][3] = -1e30f; }
        }
      }
    }
#pragma unroll
    for (int f = 0; f < 2; ++f) {
#pragma unroll
      for (int i = 0; i < 4; ++i) {
        float m2 = fmaxf(fmaxf(sc[f][0][i], sc[f][1][i]), fmaxf(sc[f][2][i], sc[f][3][i]));
        m2 = fmaxf(m2, __shfl_xor(m2, 1));
        m2 = fmaxf(m2, __shfl_xor(m2, 2));
        m2 = fmaxf(m2, __shfl_xor(m2, 4));
        m2 = fmaxf(m2, __shfl_xor(m2, 8));
        float mn = fmaxf(mrow[f][i], m2);
        float sf = exp2f(mrow[f][i] - mn);
        mrow[f][i] = mn;
        float sum = 0.f;
#pragma unroll
        for (int nt = 0; nt < 4; ++nt) {
          float e = exp2f(sc[f][nt][i] - mn);
          sum += e;
          Pb[w][f * 16 + lh * 4 + i][nt * 16 + l15] = f2bf(e);
        }
        sum += __shfl_xor(sum, 1);
        sum += __shfl_xor(sum, 2);
        sum += __shfl_xor(sum, 4);
        sum += __shfl_xor(sum, 8);
        lrow[f][i] = lrow[f][i] * sf + sum;
#pragma unroll
        for (int dt = 0; dt < 4; ++dt) acc[f][dt][i] *= sf;
      }
    }
#pragma unroll
    for (int kk2 = 0; kk2 < 2; ++kk2) {
      const short* vp = vt + vbase + kb + kk2 * 32 + lh * 8;
      s8v af0 = *(const s8v*)&Pb[w][l15][kk2 * 32 + lh * 8];
      s8v af1 = *(const s8v*)&Pb[w][16 + l15][kk2 * 32 + lh * 8];
#pragma unroll
      for (int dt = 0; dt < 4; ++dt) {
        s8v bf = *(const s8v*)(vp + (size_t)(dt * 16 + l15) * SPAD);
        acc[0][dt] = MFMA16(af0, bf, acc[0][dt]);
        acc[1][dt] = MFMA16(af1, bf, acc[1][dt]);
      }
    }
#pragma unroll
    for (int nt = 0; nt < 4; ++nt) { kf0[nt] = kn0[nt]; kf1[nt] = kn1[nt]; }
  }
#undef LOADK
#pragma unroll
  for (int f = 0; f < 2; ++f)
#pragma unroll
    for (int i = 0; i < 4; ++i) {
      int srow = q0 + f * 16 + lh * 4 + i;
      if (srow > 576) continue;
      float inv = 1.f / lrow[f][i];
      size_t idx0 = ((size_t)b * S_LEN + srow) * DMODEL + h * DHEAD + l15;
#pragma unroll
      for (int dt = 0; dt < 4; ++dt) {
        size_t idx = idx0 + dt * 16;
        outp[idx] = x[idx] + acc[f][dt][i] * inv;
      }
    }
}

// ===== 128x128 GEMM, BK=32, 3-deep prefetch, counted vmcnt, raw barriers (no vmcnt(0) drain) =====
// Per stage per thread: 4 gload16 (2 A-chunks + 2 B-chunks). Steady state: 3 stages issued,
// wait vmcnt(8) => oldest stage's 4 loads retired (in-order retirement, m135).
#define GEMM_BODY                                                                 \
  int n0 = blockIdx.x * 128, m0 = blockIdx.y * 128;                               \
  int t = threadIdx.x;                                                            \
  int w = t >> 6, l = t & 63, l15 = l & 15, lh = l >> 4;                          \
  int wr = w >> 1, wc = w & 1;                                                    \
  int sr = w * 32 + (l >> 2);          /* chunk0 row; chunk1 = sr+16 */           \
  int scol = (l & 3) * 8;                                                         \
  short* dA0 = &sA[0][0][0] + w * 1024;                                           \
  short* dB0 = &sB[0][0][0] + w * 1024;                                           \
  f4v z = {0.f, 0.f, 0.f, 0.f};                                                   \
  f4v acc[4][4];                                                                  \
  _Pragma("unroll") for (int i = 0; i < 4; ++i)                                   \
    _Pragma("unroll") for (int j = 0; j < 4; ++j) acc[i][j] = z;                  \
  int ntile = K >> 5;                                                             \
  _Pragma("unroll") for (int p = 0; p < 3; ++p) {                                 \
    const short* gA = A  + (size_t)(m0 + sr) * K + p * 32 + scol;                 \
    const short* gB = Bt + (size_t)(n0 + sr) * K + p * 32 + scol;                 \
    gload16(gA, dA0 + p * 4096);                                                  \
    gload16(gA + (size_t)16 * K, dA0 + p * 4096 + 512);                           \
    gload16(gB, dB0 + p * 4096);                                                  \
    gload16(gB + (size_t)16 * K, dB0 + p * 4096 + 512);                           \
  }                                                                               \
  int cur = 0;                                                                    \
  for (int ts = 0; ts < ntile; ++ts) {                                            \
    if (ts < ntile - 2)       { asm volatile("s_waitcnt vmcnt(8)" ::: "memory"); }\
    else if (ts == ntile - 2) { asm volatile("s_waitcnt vmcnt(4)" ::: "memory"); }\
    else                      { asm volatile("s_waitcnt vmcnt(0)" ::: "memory"); }\
    __builtin_amdgcn_s_barrier();                                                 \
    asm volatile("" ::: "memory");                                                \
    {                                                                             \
      s8v af[4], bf[4];                                                           \
      _Pragma("unroll") for (int mt = 0; mt < 4; ++mt)                            \
        af[mt] = *(const s8v*)&sA[cur][wr * 64 + mt * 16 + l15][lh * 8];          \
      _Pragma("unroll") for (int nn = 0; nn < 4; ++nn)                            \
        bf[nn] = *(const s8v*)&sB[cur][wc * 64 + nn * 16 + l15][lh * 8];          \
      _Pragma("unroll") for (int mt = 0; mt < 4; ++mt)                            \
        _Pragma("unroll") for (int nn = 0; nn < 4; ++nn)                          \
          acc[mt][nn] = MFMA16(af[mt], bf[nn], acc[mt][nn]);                      \
    }                                                                             \
    asm volatile("" ::: "memory");                                                \
    __builtin_amdgcn_s_barrier();                                                 \
    asm volatile("" ::: "memory");                                                \
    if (ts + 3 < ntile) {                                                         \
      const short* gA = A  + (size_t)(m0 + sr) * K + (ts + 3) * 32 + scol;        \
      const short* gB = Bt + (size_t)(n0 + sr) * K + (ts + 3) * 32 + scol;        \
      short* dA = dA0 + cur * 4096;                                               \
      short* dB = dB0 + cur * 4096;                                               \
      gload16(gA, dA);                                                            \
      gload16(gA + (size_t)16 * K, dA + 512);                                     \
      gload16(gB, dB);                                                            \
      gload16(gB + (size_t)16 * K, dB + 512);                                     \
    }                                                                             \
    cur = (cur == 2) ? 0 : cur + 1;                                               \
  }

// ---------------- GEMM + bias + GELU (sigmoid-form tanh approx) -> bf16 ----------------
__global__ __launch_bounds__(256, 3) void gemm_gelu(const short* __restrict__ A, const short* __restrict__ Bt,
                                                    const float* __restrict__ bias, short* __restrict__ C,
                                                    int M, int N, int K) {
  __shared__ __align__(16) short sA[3][128][32];
  __shared__ __align__(16) short sB[3][128][32];
  GEMM_BODY
#pragma unroll
  for (int mt = 0; mt < 4; ++mt)
#pragma unroll
    for (int nn = 0; nn < 4; ++nn) {
      int col = n0 + wc * 64 + nn * 16 + l15;
      float bi = bias[col];
#pragma unroll
      for (int i = 0; i < 4; ++i) {
        int row = m0 + wr * 64 + mt * 16 + lh * 4 + i;
        float v = acc[mt][nn][i] + bi;
        float u = v * (2.30221838f + 0.10294364f * v * v);
        v = v / (1.f + exp2f(-u));
        C[(size_t)row * N + col] = f2bf(v);
      }
    }
}

// ---------------- GEMM + bias + residual (in-place on out) ----------------
__global__ __launch_bounds__(256, 3) void gemm_res(const short* __restrict__ A, const short* __restrict__ Bt,
                                                   const float* __restrict__ bias, float* __restrict__ outp,
                                                   int Mvalid, int N, int K) {
  __shared__ __align__(16) short sA[3][128][32];
  __shared__ __align__(16) short sB[3][128][32];
  GEMM_BODY
#pragma unroll
  for (int mt = 0; mt < 4; ++mt)
#pragma unroll
    for (int nn = 0; nn < 4; ++nn) {
      int col = n0 + wc * 64 + nn * 16 + l15;
      float bi = bias[col];
#pragma unroll
      for (int i = 0; i < 4; ++i) {
        int row = m0 + wr * 64 + mt * 16 + lh * 4 + i;
        if (row < Mvalid) {
          size_t idx = (size_t)row * N + col;
          outp[idx] += acc[mt][nn][i] + bi;
        }
      }
    }
}

extern "C" void kernel_launch(void* const* d_in, const int* in_sizes, int n_in,
                              void* d_out, int out_size, void* d_ws, size_t ws_size,
                              hipStream_t stream) {
  const float* x    = (const float*)d_in[0];
  const float* ln1g = (const float*)d_in[1];
  const float* ln1b = (const float*)d_in[2];
  const float* ln2g = (const float*)d_in[3];
  const float* ln2b = (const float*)d_in[4];
  const float* wq   = (const float*)d_in[5];
  const float* bq   = (const float*)d_in[6];
  const float* wk   = (const float*)d_in[7];
  const float* bk   = (const float*)d_in[8];
  const float* wv   = (const float*)d_in[9];
  const float* bv   = (const float*)d_in[10];
  const float* w1   = (const float*)d_in[11];
  const float* b1   = (const float*)d_in[12];
  const float* w2   = (const float*)d_in[13];
  const float* b2   = (const float*)d_in[14];
  float* outp = (float*)d_out;

  // ---- workspace layout with aliasing (peak ~148 MiB) ----
  char* ws = (char*)d_ws;
  size_t off = 0;
  auto carve = [&](size_t elems) -> short* {
    short* p = (short*)(ws + off);
    off += elems * sizeof(short);
    off = (off + 255) & ~(size_t)255;
    return p;
  };
  short* yn   = carve((size_t)MPAD * DMODEL);
  short* w1t  = carve((size_t)MLPD * DMODEL);
  short* w2t  = carve((size_t)DMODEL * MLPD);
  short* wqt  = carve((size_t)NH * 64 * 64);
  short* wkt  = carve((size_t)NH * 64 * 64);
  short* wvt  = carve((size_t)NH * 64 * 64);
  size_t union_base = off;
  short* hbuf = carve((size_t)MPAD * MLPD);           // phase B
  off = union_base;                                    // phase A aliases
  short* xn   = carve((size_t)NROWS * DMODEL);
  short* qg   = carve((size_t)NBH * S_LEN * DHEAD);
  short* kg   = carve((size_t)NBH * S_LEN * DHEAD);
  short* vtb  = carve((size_t)NBH * DHEAD * SPAD);
  (void)ws_size; (void)in_sizes; (void)n_in; (void)out_size;

  // prep weights
  transpose_w<<<dim3(MLPD / 32, DMODEL / 32), dim3(32, 8), 0, stream>>>(w1, w1t, DMODEL, MLPD);
  transpose_w<<<dim3(DMODEL / 32, MLPD / 32), dim3(32, 8), 0, stream>>>(w2, w2t, MLPD, DMODEL);
  prep_qkv<<<NH, 256, 0, stream>>>(wq, wk, wv, wqt, wkt, wvt);
  pad_vt<<<(NBH * DHEAD * (SPAD - S_LEN) + 255) / 256, 256, 0, stream>>>(vtb);

  // LN1 -> xn (bf16)
  ln_kernel<<<NROWS, 256, 0, stream>>>(x, ln1g, ln1b, xn);

  // QKV projections (V transposed to [bh][d][s])
  qkv_kernel<<<((NROWS + 63) / 64) * NH, 256, 0, stream>>>(xn, wqt, wkt, wvt, bq, bk, bv, qg, kg, vtb);

  // attention + residual1 -> d_out
  attn_kernel<<<dim3(NBH, 5), 256, 0, stream>>>(qg, kg, vtb, x, outp);

  // LN2 -> yn
  ln_kernel<<<NROWS, 256, 0, stream>>>(outp, ln2g, ln2b, yn);

  // MLP (grid: x = n-tile fast => column tiles of one m-row run concurrently, A fetched once)
  gemm_gelu<<<dim3(MLPD / 128, MPAD / 128), 256, 0, stream>>>(yn, w1t, b1, hbuf, MPAD, MLPD, DMODEL);
  gemm_res<<<dim3(DMODEL / 128, MPAD / 128), 256, 0, stream>>>(hbuf, w2t, b2, outp, NROWS, DMODEL, MLPD);
}

// Round 7
// 563.196 us; speedup vs baseline: 1.4442x; 1.0221x over previous
//
#include <hip/hip_runtime.h>

#define S_LEN 577
#define SPAD  640
#define DMODEL 768
#define NH 12
#define DHEAD 64
#define MLPD 3072
#define NROWS (32 * 577)      // 18464
#define MPAD  18560           // 145*128
#define NBH   (32 * 12)       // 384
#define LOG2E 1.44269504088896340736f

typedef __attribute__((ext_vector_type(8))) short s8v;
typedef __attribute__((ext_vector_type(4))) float f4v;

#define MFMA16(a, b, c) __builtin_amdgcn_mfma_f32_16x16x32_bf16((a), (b), (c), 0, 0, 0)

__device__ __forceinline__ short f2bf(float f) {
  union { float f; unsigned u; } a; a.f = f;
  unsigned r = a.u + 0x7FFFu + ((a.u >> 16) & 1u);
  return (short)(r >> 16);
}

__device__ __forceinline__ void gload16(const short* g, const short* l) {
  __builtin_amdgcn_global_load_lds(
      (const __attribute__((address_space(1))) void*)g,
      (__attribute__((address_space(3))) void*)l, 16, 0, 0);
}

// ---------------- prep: transpose fp32 (R,C) -> bf16 (C,R) ----------------
__global__ __launch_bounds__(256) void transpose_w(const float* __restrict__ in,
                                                   short* __restrict__ out, int R, int C) {
  __shared__ float tile[32][33];
  int c0 = blockIdx.x * 32, r0 = blockIdx.y * 32;
  int tx = threadIdx.x, ty = threadIdx.y;
  for (int i = ty; i < 32; i += 8) tile[i][tx] = in[(size_t)(r0 + i) * C + c0 + tx];
  __syncthreads();
  for (int i = ty; i < 32; i += 8) out[(size_t)(c0 + i) * R + r0 + tx] = f2bf(tile[tx][i]);
}

// ---------------- prep: per-head (d,o) -> bf16 (o,d) for wq/wk/wv ----------------
__global__ __launch_bounds__(256) void prep_qkv(const float* __restrict__ wq, const float* __restrict__ wk,
                                                const float* __restrict__ wv, short* __restrict__ oq,
                                                short* __restrict__ ok, short* __restrict__ ov) {
  int h = blockIdx.x, t = threadIdx.x;
  const float* src0 = wq + (size_t)h * 4096;
  const float* src1 = wk + (size_t)h * 4096;
  const float* src2 = wv + (size_t)h * 4096;
  short* dst0 = oq + (size_t)h * 4096;
  short* dst1 = ok + (size_t)h * 4096;
  short* dst2 = ov + (size_t)h * 4096;
  for (int i = t; i < 4096; i += 256) {
    int o = i >> 6, d = i & 63;
    dst0[i] = f2bf(src0[d * 64 + o]);
    dst1[i] = f2bf(src1[d * 64 + o]);
    dst2[i] = f2bf(src2[d * 64 + o]);
  }
}

// ---------------- zero the s-padding of vt: [NBH][64][SPAD], s in [577,640) ----------------
__global__ __launch_bounds__(256) void pad_vt(short* __restrict__ vt) {
  int idx = blockIdx.x * 256 + threadIdx.x;
  const int padw = SPAD - S_LEN;          // 63
  const int per = DHEAD * padw;           // 4032
  if (idx >= NBH * per) return;
  int bh = idx / per, r = idx - bh * per;
  int col = r / padw, s = S_LEN + (r - col * padw);
  vt[((size_t)bh * DHEAD + col) * SPAD + s] = 0;
}

// ---------------- LayerNorm (D=768), fp32 in -> bf16 out ----------------
__global__ __launch_bounds__(256) void ln_kernel(const float* __restrict__ x, const float* __restrict__ g,
                                                 const float* __restrict__ bta, short* __restrict__ out) {
  int row = blockIdx.x;
  int t = threadIdx.x;
  const float* xr = x + (size_t)row * DMODEL;
  float v0 = xr[t], v1 = xr[t + 256], v2 = xr[t + 512];
  float s = v0 + v1 + v2;
  float s2 = v0 * v0 + v1 * v1 + v2 * v2;
  for (int o = 32; o; o >>= 1) { s += __shfl_down(s, o); s2 += __shfl_down(s2, o); }
  __shared__ float red[8];
  if ((t & 63) == 0) { int w = t >> 6; red[w] = s; red[4 + w] = s2; }
  __syncthreads();
  s = red[0] + red[1] + red[2] + red[3];
  s2 = red[4] + red[5] + red[6] + red[7];
  float m = s * (1.f / DMODEL);
  float rs = rsqrtf(s2 * (1.f / DMODEL) - m * m + 1e-5f);
  short* orow = out + (size_t)row * DMODEL;
  orow[t]       = f2bf((v0 - m) * rs * g[t]       + bta[t]);
  orow[t + 256] = f2bf((v1 - m) * rs * g[t + 256] + bta[t + 256]);
  orow[t + 512] = f2bf((v2 - m) * rs * g[t + 512] + bta[t + 512]);
}

// ---------------- QKV: per-head 64x64 GEMM, bias; q pre-scaled (1/8)*log2e; V transposed ----------------
__global__ __launch_bounds__(256) void qkv_kernel(const short* __restrict__ xn,
    const short* __restrict__ wqt, const short* __restrict__ wkt, const short* __restrict__ wvt,
    const float* __restrict__ bq, const float* __restrict__ bk, const float* __restrict__ bv,
    short* __restrict__ qg, short* __restrict__ kg, short* __restrict__ vt) {
  __shared__ __align__(16) short wl[3][64][72];
  int bid = blockIdx.x;
  int h = bid % NH, mt = bid / NH;
  int t = threadIdx.x;
  {
    int o = t >> 2, d0 = (t & 3) * 16;
    const short* s0 = wqt + (size_t)h * 4096 + o * 64 + d0;
    const short* s1 = wkt + (size_t)h * 4096 + o * 64 + d0;
    const short* s2 = wvt + (size_t)h * 4096 + o * 64 + d0;
    *(uint4*)&wl[0][o][d0]     = *(const uint4*)s0;
    *(uint4*)&wl[0][o][d0 + 8] = *(const uint4*)(s0 + 8);
    *(uint4*)&wl[1][o][d0]     = *(const uint4*)s1;
    *(uint4*)&wl[1][o][d0 + 8] = *(const uint4*)(s1 + 8);
    *(uint4*)&wl[2][o][d0]     = *(const uint4*)s2;
    *(uint4*)&wl[2][o][d0 + 8] = *(const uint4*)(s2 + 8);
  }
  __syncthreads();
  int w = t >> 6, l = t & 63, l15 = l & 15, lh = l >> 4;
  int m0 = mt * 64 + w * 16;
  if (m0 >= NROWS) return;
  f4v z = {0.f, 0.f, 0.f, 0.f};
  f4v aq[4], ak[4], av[4];
#pragma unroll
  for (int nt = 0; nt < 4; ++nt) { aq[nt] = z; ak[nt] = z; av[nt] = z; }
  const short* xrow = xn + (size_t)(m0 + l15) * DMODEL + h * DHEAD;
#pragma unroll
  for (int kk = 0; kk < 64; kk += 32) {
    s8v af = *(const s8v*)(xrow + kk + lh * 8);
#pragma unroll
    for (int nt = 0; nt < 4; ++nt) {
      s8v b0 = *(const s8v*)&wl[0][nt * 16 + l15][kk + lh * 8];
      s8v b1 = *(const s8v*)&wl[1][nt * 16 + l15][kk + lh * 8];
      s8v b2 = *(const s8v*)&wl[2][nt * 16 + l15][kk + lh * 8];
      aq[nt] = MFMA16(af, b0, aq[nt]);
      ak[nt] = MFMA16(af, b1, ak[nt]);
      av[nt] = MFMA16(af, b2, av[nt]);
    }
  }
#pragma unroll
  for (int nt = 0; nt < 4; ++nt) {
    int col = nt * 16 + l15;
    float biq = bq[h * DHEAD + col], bik = bk[h * DHEAD + col], biv = bv[h * DHEAD + col];
#pragma unroll
    for (int i = 0; i < 4; ++i) {
      int m = m0 + lh * 4 + i;
      int bb = m / S_LEN;
      int ss = m - bb * S_LEN;
      int bh = bb * NH + h;
      size_t ob = ((size_t)bh * S_LEN + ss) * DHEAD + col;
      qg[ob] = f2bf((aq[nt][i] + biq) * (0.125f * LOG2E));
      kg[ob] = f2bf(ak[nt][i] + bik);
      vt[((size_t)bh * DHEAD + col) * SPAD + ss] = f2bf(av[nt][i] + biv);
    }
  }
}

// ---------------- attention: flash-style, 32 q-rows/wave, K-reg prefetch, exp2 softmax ----------------
__global__ __launch_bounds__(256) void attn_kernel(const short* __restrict__ qg, const short* __restrict__ kg,
                                                   const short* __restrict__ vt, const float* __restrict__ x,
                                                   float* __restrict__ outp) {
  __shared__ __align__(16) short Pb[4][32][72];
  int bh = blockIdx.x;       // 0..383
  int qt = blockIdx.y;       // 0..4
  int h = bh % NH, b = bh / NH;
  int t = threadIdx.x, w = t >> 6, l = t & 63, l15 = l & 15, lh = l >> 4;
  int q0 = qt * 128 + w * 32;
  if (q0 > 576) return;
  size_t base  = (size_t)bh * S_LEN * DHEAD;
  size_t vbase = (size_t)bh * DHEAD * SPAD;
  s8v aq[2][2];
#pragma unroll
  for (int f = 0; f < 2; ++f) {
    int qrow = q0 + f * 16 + l15; if (qrow > 576) qrow = 576;
    const short* qp = qg + base + (size_t)qrow * DHEAD + lh * 8;
    aq[f][0] = *(const s8v*)qp;
    aq[f][1] = *(const s8v*)(qp + 32);
  }
  f4v z = {0.f, 0.f, 0.f, 0.f};
  f4v acc[2][4];
  float mrow[2][4], lrow[2][4];
#pragma unroll
  for (int f = 0; f < 2; ++f) {
#pragma unroll
    for (int dt = 0; dt < 4; ++dt) acc[f][dt] = z;
#pragma unroll
    for (int i = 0; i < 4; ++i) { mrow[f][i] = -1e30f; lrow[f][i] = 0.f; }
  }

#define LOADK(KB, K0, K1)                                              \
  {                                                                    \
    _Pragma("unroll")                                                  \
    for (int nt = 0; nt < 4; ++nt) {                                   \
      int key = (KB) + nt * 16 + l15; if (key > 576) key = 576;        \
      const short* kp = kg + base + (size_t)key * DHEAD + lh * 8;      \
      K0[nt] = *(const s8v*)kp;                                        \
      K1[nt] = *(const s8v*)(kp + 32);                                 \
    }                                                                  \
  }

  s8v kf0[4], kf1[4];
  LOADK(0, kf0, kf1);

  for (int kt = 0; kt < 10; ++kt) {
    int kb = kt * 64;
    f4v sc[2][4];
#pragma unroll
    for (int nt = 0; nt < 4; ++nt) {
#pragma unroll
      for (int f = 0; f < 2; ++f) {
        f4v a = z;
        a = MFMA16(aq[f][0], kf0[nt], a);
        a = MFMA16(aq[f][1], kf1[nt], a);
        sc[f][nt] = a;
      }
    }
    s8v kn0[4], kn1[4];
    if (kt < 9) LOADK(kb + 64, kn0, kn1);
    if (kt == 9) {
#pragma unroll
      for (int nt = 0; nt < 4; ++nt) {
        int col = kb + nt * 16 + l15;
        if (col > 576) {
#pragma unroll
          for (int f = 0; f < 2; ++f) { sc[f][nt][0] = sc[f][nt][1] = sc[f][nt][2] = sc[f][nt][3] = -1e30f; }
        }
      }
    }
#pragma unroll
    for (int f = 0; f < 2; ++f) {
#pragma unroll
      for (int i = 0; i < 4; ++i) {
        float m2 = fmaxf(fmaxf(sc[f][0][i], sc[f][1][i]), fmaxf(sc[f][2][i], sc[f][3][i]));
        m2 = fmaxf(m2, __shfl_xor(m2, 1));
        m2 = fmaxf(m2, __shfl_xor(m2, 2));
        m2 = fmaxf(m2, __shfl_xor(m2, 4));
        m2 = fmaxf(m2, __shfl_xor(m2, 8));
        float mn = fmaxf(mrow[f][i], m2);
        float sf = exp2f(mrow[f][i] - mn);
        mrow[f][i] = mn;
        float sum = 0.f;
#pragma unroll
        for (int nt = 0; nt < 4; ++nt) {
          float e = exp2f(sc[f][nt][i] - mn);
          sum += e;
          Pb[w][f * 16 + lh * 4 + i][nt * 16 + l15] = f2bf(e);
        }
        sum += __shfl_xor(sum, 1);
        sum += __shfl_xor(sum, 2);
        sum += __shfl_xor(sum, 4);
        sum += __shfl_xor(sum, 8);
        lrow[f][i] = lrow[f][i] * sf + sum;
#pragma unroll
        for (int dt = 0; dt < 4; ++dt) acc[f][dt][i] *= sf;
      }
    }
#pragma unroll
    for (int kk2 = 0; kk2 < 2; ++kk2) {
      const short* vp = vt + vbase + kb + kk2 * 32 + lh * 8;
      s8v af0 = *(const s8v*)&Pb[w][l15][kk2 * 32 + lh * 8];
      s8v af1 = *(const s8v*)&Pb[w][16 + l15][kk2 * 32 + lh * 8];
#pragma unroll
      for (int dt = 0; dt < 4; ++dt) {
        s8v bf = *(const s8v*)(vp + (size_t)(dt * 16 + l15) * SPAD);
        acc[0][dt] = MFMA16(af0, bf, acc[0][dt]);
        acc[1][dt] = MFMA16(af1, bf, acc[1][dt]);
      }
    }
#pragma unroll
    for (int nt = 0; nt < 4; ++nt) { kf0[nt] = kn0[nt]; kf1[nt] = kn1[nt]; }
  }
#undef LOADK
#pragma unroll
  for (int f = 0; f < 2; ++f)
#pragma unroll
    for (int i = 0; i < 4; ++i) {
      int srow = q0 + f * 16 + lh * 4 + i;
      if (srow > 576) continue;
      float inv = 1.f / lrow[f][i];
      size_t idx0 = ((size_t)b * S_LEN + srow) * DMODEL + h * DHEAD + l15;
#pragma unroll
      for (int dt = 0; dt < 4; ++dt) {
        size_t idx = idx0 + dt * 16;
        outp[idx] = x[idx] + acc[f][dt][i] * inv;
      }
    }
}

// ===== 128x128 GEMM, BK=32, 3-deep prefetch, counted vmcnt, raw barriers,
//       LDS XOR-swizzle (pre-swizzled global source + swizzled ds_read),
//       bijective XCD-chunked 1-D grid (n-fastest within chunk) =====
#define GEMM_BODY                                                                 \
  int nwg = gridDim.x;                                                            \
  int orig = blockIdx.x;                                                          \
  int qq = nwg >> 3, rr = nwg & 7;                                                \
  int xcd = orig & 7, lin = orig >> 3;                                            \
  int wg = (xcd < rr ? xcd * (qq + 1) : rr * (qq + 1) + (xcd - rr) * qq) + lin;   \
  int nx = N >> 7;                                                                \
  int n0 = (wg % nx) * 128, m0 = (wg / nx) * 128;                                 \
  int t = threadIdx.x;                                                            \
  int w = t >> 6, l = t & 63, l15 = l & 15, lh = l >> 4;                          \
  int wr = w >> 1, wc = w & 1;                                                    \
  int sr = w * 32 + (l >> 2);          /* chunk0 row; chunk1 = sr+16 */           \
  int scol = (((l & 3) ^ ((l >> 3) & 3)) * 8);   /* pre-swizzled source col */    \
  int swz8 = ((lh ^ ((l15 >> 1) & 3)) * 8);      /* swizzled ds_read col  */      \
  short* dA0 = &sA[0][0][0] + w * 1024;                                           \
  short* dB0 = &sB[0][0][0] + w * 1024;                                           \
  f4v z = {0.f, 0.f, 0.f, 0.f};                                                   \
  f4v acc[4][4];                                                                  \
  _Pragma("unroll") for (int i = 0; i < 4; ++i)                                   \
    _Pragma("unroll") for (int j = 0; j < 4; ++j) acc[i][j] = z;                  \
  int ntile = K >> 5;                                                             \
  _Pragma("unroll") for (int p = 0; p < 3; ++p) {                                 \
    const short* gA = A  + (size_t)(m0 + sr) * K + p * 32 + scol;                 \
    const short* gB = Bt + (size_t)(n0 + sr) * K + p * 32 + scol;                 \
    gload16(gA, dA0 + p * 4096);                                                  \
    gload16(gA + (size_t)16 * K, dA0 + p * 4096 + 512);                           \
    gload16(gB, dB0 + p * 4096);                                                  \
    gload16(gB + (size_t)16 * K, dB0 + p * 4096 + 512);                           \
  }                                                                               \
  int cur = 0;                                                                    \
  for (int ts = 0; ts < ntile; ++ts) {                                            \
    if (ts < ntile - 2)       { asm volatile("s_waitcnt vmcnt(8)" ::: "memory"); }\
    else if (ts == ntile - 2) { asm volatile("s_waitcnt vmcnt(4)" ::: "memory"); }\
    else                      { asm volatile("s_waitcnt vmcnt(0)" ::: "memory"); }\
    __builtin_amdgcn_s_barrier();                                                 \
    asm volatile("" ::: "memory");                                                \
    {                                                                             \
      s8v af[4], bf[4];                                                           \
      _Pragma("unroll") for (int mt = 0; mt < 4; ++mt)                            \
        af[mt] = *(const s8v*)&sA[cur][wr * 64 + mt * 16 + l15][swz8];            \
      _Pragma("unroll") for (int nn = 0; nn < 4; ++nn)                            \
        bf[nn] = *(const s8v*)&sB[cur][wc * 64 + nn * 16 + l15][swz8];            \
      _Pragma("unroll") for (int mt = 0; mt < 4; ++mt)                            \
        _Pragma("unroll") for (int nn = 0; nn < 4; ++nn)                          \
          acc[mt][nn] = MFMA16(af[mt], bf[nn], acc[mt][nn]);                      \
    }                                                                             \
    asm volatile("" ::: "memory");                                                \
    __builtin_amdgcn_s_barrier();                                                 \
    asm volatile("" ::: "memory");                                                \
    if (ts + 3 < ntile) {                                                         \
      const short* gA = A  + (size_t)(m0 + sr) * K + (ts + 3) * 32 + scol;        \
      const short* gB = Bt + (size_t)(n0 + sr) * K + (ts + 3) * 32 + scol;        \
      short* dA = dA0 + cur * 4096;                                               \
      short* dB = dB0 + cur * 4096;                                               \
      gload16(gA, dA);                                                            \
      gload16(gA + (size_t)16 * K, dA + 512);                                     \
      gload16(gB, dB);                                                            \
      gload16(gB + (size_t)16 * K, dB + 512);                                     \
    }                                                                             \
    cur = (cur == 2) ? 0 : cur + 1;                                               \
  }

// ---------------- GEMM + bias + GELU (sigmoid-form tanh approx) -> bf16 ----------------
__global__ __launch_bounds__(256, 3) void gemm_gelu(const short* __restrict__ A, const short* __restrict__ Bt,
                                                    const float* __restrict__ bias, short* __restrict__ C,
                                                    int M, int N, int K) {
  __shared__ __align__(16) short sA[3][128][32];
  __shared__ __align__(16) short sB[3][128][32];
  GEMM_BODY
#pragma unroll
  for (int mt = 0; mt < 4; ++mt)
#pragma unroll
    for (int nn = 0; nn < 4; ++nn) {
      int col = n0 + wc * 64 + nn * 16 + l15;
      float bi = bias[col];
#pragma unroll
      for (int i = 0; i < 4; ++i) {
        int row = m0 + wr * 64 + mt * 16 + lh * 4 + i;
        float v = acc[mt][nn][i] + bi;
        float u = v * (2.30221838f + 0.10294364f * v * v);
        v = v / (1.f + exp2f(-u));
        C[(size_t)row * N + col] = f2bf(v);
      }
    }
}

// ---------------- GEMM + bias + residual (in-place on out) ----------------
__global__ __launch_bounds__(256, 3) void gemm_res(const short* __restrict__ A, const short* __restrict__ Bt,
                                                   const float* __restrict__ bias, float* __restrict__ outp,
                                                   int Mvalid, int N, int K) {
  __shared__ __align__(16) short sA[3][128][32];
  __shared__ __align__(16) short sB[3][128][32];
  GEMM_BODY
#pragma unroll
  for (int mt = 0; mt < 4; ++mt)
#pragma unroll
    for (int nn = 0; nn < 4; ++nn) {
      int col = n0 + wc * 64 + nn * 16 + l15;
      float bi = bias[col];
#pragma unroll
      for (int i = 0; i < 4; ++i) {
        int row = m0 + wr * 64 + mt * 16 + lh * 4 + i;
        if (row < Mvalid) {
          size_t idx = (size_t)row * N + col;
          outp[idx] += acc[mt][nn][i] + bi;
        }
      }
    }
}

extern "C" void kernel_launch(void* const* d_in, const int* in_sizes, int n_in,
                              void* d_out, int out_size, void* d_ws, size_t ws_size,
                              hipStream_t stream) {
  const float* x    = (const float*)d_in[0];
  const float* ln1g = (const float*)d_in[1];
  const float* ln1b = (const float*)d_in[2];
  const float* ln2g = (const float*)d_in[3];
  const float* ln2b = (const float*)d_in[4];
  const float* wq   = (const float*)d_in[5];
  const float* bq   = (const float*)d_in[6];
  const float* wk   = (const float*)d_in[7];
  const float* bk   = (const float*)d_in[8];
  const float* wv   = (const float*)d_in[9];
  const float* bv   = (const float*)d_in[10];
  const float* w1   = (const float*)d_in[11];
  const float* b1   = (const float*)d_in[12];
  const float* w2   = (const float*)d_in[13];
  const float* b2   = (const float*)d_in[14];
  float* outp = (float*)d_out;

  // ---- workspace layout with aliasing (peak ~148 MiB) ----
  char* ws = (char*)d_ws;
  size_t off = 0;
  auto carve = [&](size_t elems) -> short* {
    short* p = (short*)(ws + off);
    off += elems * sizeof(short);
    off = (off + 255) & ~(size_t)255;
    return p;
  };
  short* yn   = carve((size_t)MPAD * DMODEL);
  short* w1t  = carve((size_t)MLPD * DMODEL);
  short* w2t  = carve((size_t)DMODEL * MLPD);
  short* wqt  = carve((size_t)NH * 64 * 64);
  short* wkt  = carve((size_t)NH * 64 * 64);
  short* wvt  = carve((size_t)NH * 64 * 64);
  size_t union_base = off;
  short* hbuf = carve((size_t)MPAD * MLPD);           // phase B
  off = union_base;                                    // phase A aliases
  short* xn   = carve((size_t)NROWS * DMODEL);
  short* qg   = carve((size_t)NBH * S_LEN * DHEAD);
  short* kg   = carve((size_t)NBH * S_LEN * DHEAD);
  short* vtb  = carve((size_t)NBH * DHEAD * SPAD);
  (void)ws_size; (void)in_sizes; (void)n_in; (void)out_size;

  // prep weights
  transpose_w<<<dim3(MLPD / 32, DMODEL / 32), dim3(32, 8), 0, stream>>>(w1, w1t, DMODEL, MLPD);
  transpose_w<<<dim3(DMODEL / 32, MLPD / 32), dim3(32, 8), 0, stream>>>(w2, w2t, MLPD, DMODEL);
  prep_qkv<<<NH, 256, 0, stream>>>(wq, wk, wv, wqt, wkt, wvt);
  pad_vt<<<(NBH * DHEAD * (SPAD - S_LEN) + 255) / 256, 256, 0, stream>>>(vtb);

  // LN1 -> xn (bf16)
  ln_kernel<<<NROWS, 256, 0, stream>>>(x, ln1g, ln1b, xn);

  // QKV projections (V transposed to [bh][d][s])
  qkv_kernel<<<((NROWS + 63) / 64) * NH, 256, 0, stream>>>(xn, wqt, wkt, wvt, bq, bk, bv, qg, kg, vtb);

  // attention + residual1 -> d_out
  attn_kernel<<<dim3(NBH, 5), 256, 0, stream>>>(qg, kg, vtb, x, outp);

  // LN2 -> yn
  ln_kernel<<<NROWS, 256, 0, stream>>>(outp, ln2g, ln2b, yn);

  // MLP (1-D grids, XCD-chunked inside the kernel)
  gemm_gelu<<<dim3((MPAD / 128) * (MLPD / 128)), 256, 0, stream>>>(yn, w1t, b1, hbuf, MPAD, MLPD, DMODEL);
  gemm_res<<<dim3((MPAD / 128) * (DMODEL / 128)), 256, 0, stream>>>(hbuf, w2t, b2, outp, NROWS, DMODEL, MLPD);
}

// Round 9
// 536.681 us; speedup vs baseline: 1.5155x; 1.0494x over previous
//
#include <hip/hip_runtime.h>

#define S_LEN 577
#define SPAD  640
#define DMODEL 768
#define NH 12
#define DHEAD 64
#define MLPD 3072
#define NROWS (32 * 577)      // 18464
#define MPAD  18688           // 73*256
#define NBH   (32 * 12)       // 384
#define LOG2E 1.44269504088896340736f

typedef __attribute__((ext_vector_type(8))) short s8v;
typedef __attribute__((ext_vector_type(4))) float f4v;

#define MFMA16(a, b, c) __builtin_amdgcn_mfma_f32_16x16x32_bf16((a), (b), (c), 0, 0, 0)

__device__ __forceinline__ short f2bf(float f) {
  union { float f; unsigned u; } a; a.f = f;
  unsigned r = a.u + 0x7FFFu + ((a.u >> 16) & 1u);
  return (short)(r >> 16);
}

__device__ __forceinline__ void gload16(const short* g, const short* l) {
  __builtin_amdgcn_global_load_lds(
      (const __attribute__((address_space(1))) void*)g,
      (__attribute__((address_space(3))) void*)l, 16, 0, 0);
}

// ---------------- prep: transpose fp32 (R,C) -> bf16 (C,R) ----------------
__global__ __launch_bounds__(256) void transpose_w(const float* __restrict__ in,
                                                   short* __restrict__ out, int R, int C) {
  __shared__ float tile[32][33];
  int c0 = blockIdx.x * 32, r0 = blockIdx.y * 32;
  int tx = threadIdx.x, ty = threadIdx.y;
  for (int i = ty; i < 32; i += 8) tile[i][tx] = in[(size_t)(r0 + i) * C + c0 + tx];
  __syncthreads();
  for (int i = ty; i < 32; i += 8) out[(size_t)(c0 + i) * R + r0 + tx] = f2bf(tile[tx][i]);
}

// ---------------- prep: per-head (d,o) -> bf16 (o,d) for wq/wk/wv ----------------
__global__ __launch_bounds__(256) void prep_qkv(const float* __restrict__ wq, const float* __restrict__ wk,
                                                const float* __restrict__ wv, short* __restrict__ oq,
                                                short* __restrict__ ok, short* __restrict__ ov) {
  int h = blockIdx.x, t = threadIdx.x;
  const float* src0 = wq + (size_t)h * 4096;
  const float* src1 = wk + (size_t)h * 4096;
  const float* src2 = wv + (size_t)h * 4096;
  short* dst0 = oq + (size_t)h * 4096;
  short* dst1 = ok + (size_t)h * 4096;
  short* dst2 = ov + (size_t)h * 4096;
  for (int i = t; i < 4096; i += 256) {
    int o = i >> 6, d = i & 63;
    dst0[i] = f2bf(src0[d * 64 + o]);
    dst1[i] = f2bf(src1[d * 64 + o]);
    dst2[i] = f2bf(src2[d * 64 + o]);
  }
}

// ---------------- zero the s-padding of vt: [NBH][64][SPAD], s in [577,640) ----------------
__global__ __launch_bounds__(256) void pad_vt(short* __restrict__ vt) {
  int idx = blockIdx.x * 256 + threadIdx.x;
  const int padw = SPAD - S_LEN;          // 63
  const int per = DHEAD * padw;           // 4032
  if (idx >= NBH * per) return;
  int bh = idx / per, r = idx - bh * per;
  int col = r / padw, s = S_LEN + (r - col * padw);
  vt[((size_t)bh * DHEAD + col) * SPAD + s] = 0;
}

// ---------------- LayerNorm (D=768), fp32 in -> bf16 out ----------------
__global__ __launch_bounds__(256) void ln_kernel(const float* __restrict__ x, const float* __restrict__ g,
                                                 const float* __restrict__ bta, short* __restrict__ out) {
  int row = blockIdx.x;
  int t = threadIdx.x;
  const float* xr = x + (size_t)row * DMODEL;
  float v0 = xr[t], v1 = xr[t + 256], v2 = xr[t + 512];
  float s = v0 + v1 + v2;
  float s2 = v0 * v0 + v1 * v1 + v2 * v2;
  for (int o = 32; o; o >>= 1) { s += __shfl_down(s, o); s2 += __shfl_down(s2, o); }
  __shared__ float red[8];
  if ((t & 63) == 0) { int w = t >> 6; red[w] = s; red[4 + w] = s2; }
  __syncthreads();
  s = red[0] + red[1] + red[2] + red[3];
  s2 = red[4] + red[5] + red[6] + red[7];
  float m = s * (1.f / DMODEL);
  float rs = rsqrtf(s2 * (1.f / DMODEL) - m * m + 1e-5f);
  short* orow = out + (size_t)row * DMODEL;
  orow[t]       = f2bf((v0 - m) * rs * g[t]       + bta[t]);
  orow[t + 256] = f2bf((v1 - m) * rs * g[t + 256] + bta[t + 256]);
  orow[t + 512] = f2bf((v2 - m) * rs * g[t + 512] + bta[t + 512]);
}

// ---------------- QKV: per-head 64x64 GEMM, bias; q pre-scaled (1/8)*log2e; V transposed ----------------
__global__ __launch_bounds__(256) void qkv_kernel(const short* __restrict__ xn,
    const short* __restrict__ wqt, const short* __restrict__ wkt, const short* __restrict__ wvt,
    const float* __restrict__ bq, const float* __restrict__ bk, const float* __restrict__ bv,
    short* __restrict__ qg, short* __restrict__ kg, short* __restrict__ vt) {
  __shared__ __align__(16) short wl[3][64][72];
  int bid = blockIdx.x;
  int h = bid % NH, mt = bid / NH;
  int t = threadIdx.x;
  {
    int o = t >> 2, d0 = (t & 3) * 16;
    const short* s0 = wqt + (size_t)h * 4096 + o * 64 + d0;
    const short* s1 = wkt + (size_t)h * 4096 + o * 64 + d0;
    const short* s2 = wvt + (size_t)h * 4096 + o * 64 + d0;
    *(uint4*)&wl[0][o][d0]     = *(const uint4*)s0;
    *(uint4*)&wl[0][o][d0 + 8] = *(const uint4*)(s0 + 8);
    *(uint4*)&wl[1][o][d0]     = *(const uint4*)s1;
    *(uint4*)&wl[1][o][d0 + 8] = *(const uint4*)(s1 + 8);
    *(uint4*)&wl[2][o][d0]     = *(const uint4*)s2;
    *(uint4*)&wl[2][o][d0 + 8] = *(const uint4*)(s2 + 8);
  }
  __syncthreads();
  int w = t >> 6, l = t & 63, l15 = l & 15, lh = l >> 4;
  int m0 = mt * 64 + w * 16;
  if (m0 >= NROWS) return;
  f4v z = {0.f, 0.f, 0.f, 0.f};
  f4v aq[4], ak[4], av[4];
#pragma unroll
  for (int nt = 0; nt < 4; ++nt) { aq[nt] = z; ak[nt] = z; av[nt] = z; }
  const short* xrow = xn + (size_t)(m0 + l15) * DMODEL + h * DHEAD;
#pragma unroll
  for (int kk = 0; kk < 64; kk += 32) {
    s8v af = *(const s8v*)(xrow + kk + lh * 8);
#pragma unroll
    for (int nt = 0; nt < 4; ++nt) {
      s8v b0 = *(const s8v*)&wl[0][nt * 16 + l15][kk + lh * 8];
      s8v b1 = *(const s8v*)&wl[1][nt * 16 + l15][kk + lh * 8];
      s8v b2 = *(const s8v*)&wl[2][nt * 16 + l15][kk + lh * 8];
      aq[nt] = MFMA16(af, b0, aq[nt]);
      ak[nt] = MFMA16(af, b1, ak[nt]);
      av[nt] = MFMA16(af, b2, av[nt]);
    }
  }
#pragma unroll
  for (int nt = 0; nt < 4; ++nt) {
    int col = nt * 16 + l15;
    float biq = bq[h * DHEAD + col], bik = bk[h * DHEAD + col], biv = bv[h * DHEAD + col];
#pragma unroll
    for (int i = 0; i < 4; ++i) {
      int m = m0 + lh * 4 + i;
      int bb = m / S_LEN;
      int ss = m - bb * S_LEN;
      int bh = bb * NH + h;
      size_t ob = ((size_t)bh * S_LEN + ss) * DHEAD + col;
      qg[ob] = f2bf((aq[nt][i] + biq) * (0.125f * LOG2E));
      kg[ob] = f2bf(ak[nt][i] + bik);
      vt[((size_t)bh * DHEAD + col) * SPAD + ss] = f2bf(av[nt][i] + biv);
    }
  }
}

// ---------------- attention: flash-style, 32 q-rows/wave, K-reg prefetch, exp2 softmax ----------------
__global__ __launch_bounds__(256) void attn_kernel(const short* __restrict__ qg, const short* __restrict__ kg,
                                                   const short* __restrict__ vt, const float* __restrict__ x,
                                                   float* __restrict__ outp) {
  __shared__ __align__(16) short Pb[4][32][72];
  int bh = blockIdx.x;       // 0..383
  int qt = blockIdx.y;       // 0..4
  int h = bh % NH, b = bh / NH;
  int t = threadIdx.x, w = t >> 6, l = t & 63, l15 = l & 15, lh = l >> 4;
  int q0 = qt * 128 + w * 32;
  if (q0 > 576) return;
  size_t base  = (size_t)bh * S_LEN * DHEAD;
  size_t vbase = (size_t)bh * DHEAD * SPAD;
  s8v aq[2][2];
#pragma unroll
  for (int f = 0; f < 2; ++f) {
    int qrow = q0 + f * 16 + l15; if (qrow > 576) qrow = 576;
    const short* qp = qg + base + (size_t)qrow * DHEAD + lh * 8;
    aq[f][0] = *(const s8v*)qp;
    aq[f][1] = *(const s8v*)(qp + 32);
  }
  f4v z = {0.f, 0.f, 0.f, 0.f};
  f4v acc[2][4];
  float mrow[2][4], lrow[2][4];
#pragma unroll
  for (int f = 0; f < 2; ++f) {
#pragma unroll
    for (int dt = 0; dt < 4; ++dt) acc[f][dt] = z;
#pragma unroll
    for (int i = 0; i < 4; ++i) { mrow[f][i] = -1e30f; lrow[f][i] = 0.f; }
  }

#define LOADK(KB, K0, K1)                                              \
  {                                                                    \
    _Pragma("unroll")                                                  \
    for (int nt = 0; nt < 4; ++nt) {                                   \
      int key = (KB) + nt * 16 + l15; if (key > 576) key = 576;        \
      const short* kp = kg + base + (size_t)key * DHEAD + lh * 8;      \
      K0[nt] = *(const s8v*)kp;                                        \
      K1[nt] = *(const s8v*)(kp + 32);                                 \
    }                                                                  \
  }

  s8v kf0[4], kf1[4];
  LOADK(0, kf0, kf1);

  for (int kt = 0; kt < 10; ++kt) {
    int kb = kt * 64;
    f4v sc[2][4];
#pragma unroll
    for (int nt = 0; nt < 4; ++nt) {
#pragma unroll
      for (int f = 0; f < 2; ++f) {
        f4v a = z;
        a = MFMA16(aq[f][0], kf0[nt], a);
        a = MFMA16(aq[f][1], kf1[nt], a);
        sc[f][nt] = a;
      }
    }
    s8v kn0[4], kn1[4];
    if (kt < 9) LOADK(kb + 64, kn0, kn1);
    if (kt == 9) {
#pragma unroll
      for (int nt = 0; nt < 4; ++nt) {
        int col = kb + nt * 16 + l15;
        if (col > 576) {
#pragma unroll
          for (int f = 0; f < 2; ++f) { sc[f][nt][0] = sc[f][nt][1] = sc[f][nt][2] = sc[f][nt][3] = -1e30f; }
        }
      }
    }
#pragma unroll
    for (int f = 0; f < 2; ++f) {
#pragma unroll
      for (int i = 0; i < 4; ++i) {
        float m2 = fmaxf(fmaxf(sc[f][0][i], sc[f][1][i]), fmaxf(sc[f][2][i], sc[f][3][i]));
        m2 = fmaxf(m2, __shfl_xor(m2, 1));
        m2 = fmaxf(m2, __shfl_xor(m2, 2));
        m2 = fmaxf(m2, __shfl_xor(m2, 4));
        m2 = fmaxf(m2, __shfl_xor(m2, 8));
        float mn = fmaxf(mrow[f][i], m2);
        float sf = exp2f(mrow[f][i] - mn);
        mrow[f][i] = mn;
        float sum = 0.f;
#pragma unroll
        for (int nt = 0; nt < 4; ++nt) {
          float e = exp2f(sc[f][nt][i] - mn);
          sum += e;
          Pb[w][f * 16 + lh * 4 + i][nt * 16 + l15] = f2bf(e);
        }
        sum += __shfl_xor(sum, 1);
        sum += __shfl_xor(sum, 2);
        sum += __shfl_xor(sum, 4);
        sum += __shfl_xor(sum, 8);
        lrow[f][i] = lrow[f][i] * sf + sum;
#pragma unroll
        for (int dt = 0; dt < 4; ++dt) acc[f][dt][i] *= sf;
      }
    }
#pragma unroll
    for (int kk2 = 0; kk2 < 2; ++kk2) {
      const short* vp = vt + vbase + kb + kk2 * 32 + lh * 8;
      s8v af0 = *(const s8v*)&Pb[w][l15][kk2 * 32 + lh * 8];
      s8v af1 = *(const s8v*)&Pb[w][16 + l15][kk2 * 32 + lh * 8];
#pragma unroll
      for (int dt = 0; dt < 4; ++dt) {
        s8v bf = *(const s8v*)(vp + (size_t)(dt * 16 + l15) * SPAD);
        acc[0][dt] = MFMA16(af0, bf, acc[0][dt]);
        acc[1][dt] = MFMA16(af1, bf, acc[1][dt]);
      }
    }
#pragma unroll
    for (int nt = 0; nt < 4; ++nt) { kf0[nt] = kn0[nt]; kf1[nt] = kn1[nt]; }
  }
#undef LOADK
#pragma unroll
  for (int f = 0; f < 2; ++f)
#pragma unroll
    for (int i = 0; i < 4; ++i) {
      int srow = q0 + f * 16 + lh * 4 + i;
      if (srow > 576) continue;
      float inv = 1.f / lrow[f][i];
      size_t idx0 = ((size_t)b * S_LEN + srow) * DMODEL + h * DHEAD + l15;
#pragma unroll
      for (int dt = 0; dt < 4; ++dt) {
        size_t idx = idx0 + dt * 16;
        outp[idx] = x[idx] + acc[f][dt][i] * inv;
      }
    }
}

// ================= 256x256 8-phase GEMM (T2+T3+T4+T5), 512 thr, BK=64, 128KB LDS ================
// FIX vs r8: A fragment rows are HALF-ALIGNED — READ_A(rh) touches only rows rh*128..rh*128+127,
// so ph2's restage of A-half0 never collides with ph3's read of A-half1.
#define BARR asm volatile("s_barrier" ::: "memory")

#define STAGE_HALF(G, SH, bufi, half, ktile)                                       \
  do {                                                                             \
    _Pragma("unroll") for (int rd = 0; rd < 2; ++rd) {                             \
      int rw_ = rd * 64 + (tid >> 3);                                              \
      int sl_ = (tid & 7) ^ (rw_ & 7);                                             \
      gload16((G) + (size_t)((half) * 128 + rw_) * K + (ktile) * 64 + sl_ * 8,     \
              &SH[bufi][(half) * 128 + rw_][(tid & 7) * 8]);                       \
    }                                                                              \
  } while (0)

#define READ_A(rh)                                                                 \
  _Pragma("unroll") for (int mt = 0; mt < 4; ++mt)                                 \
    _Pragma("unroll") for (int kh = 0; kh < 2; ++kh)                               \
      af[mt][kh] = *(const s8v*)&sA[cur][(rh) * 128 + wr * 64 + mt * 16 + l15]     \
                                    [((kh * 4 + lh) ^ s7) * 8];

#define READ_B(BF, chh)                                                            \
  _Pragma("unroll") for (int nt = 0; nt < 2; ++nt)                                 \
    _Pragma("unroll") for (int kh = 0; kh < 2; ++kh)                               \
      BF[nt][kh] = *(const s8v*)&sB[cur][wc * 64 + (chh) * 32 + nt * 16 + l15]     \
                                    [((kh * 4 + lh) ^ s7) * 8];

#define DO_MFMA(rh, ch, BF)                                                        \
  __builtin_amdgcn_s_setprio(1);                                                   \
  _Pragma("unroll") for (int mt = 0; mt < 4; ++mt)                                 \
    _Pragma("unroll") for (int nt = 0; nt < 2; ++nt)                               \
      _Pragma("unroll") for (int kh = 0; kh < 2; ++kh)                             \
        acc[(rh) * 4 + mt][(ch) * 2 + nt] =                                        \
            MFMA16(af[mt][kh], BF[nt][kh], acc[(rh) * 4 + mt][(ch) * 2 + nt]);     \
  __builtin_amdgcn_s_setprio(0);

// prologue + 8-phase main loop; leaves acc[8][4] ready
#define GEMM8_BODY                                                                 \
  int nwg = gridDim.x;                                                             \
  int orig = blockIdx.x;                                                           \
  int qq = nwg >> 3, rr = nwg & 7;                                                 \
  int xcd = orig & 7, lin = orig >> 3;                                             \
  int wg = (xcd < rr ? xcd * (qq + 1) : rr * (qq + 1) + (xcd - rr) * qq) + lin;    \
  int nx = N >> 8;                                                                 \
  int n0 = (wg % nx) * 256, m0 = (wg / nx) * 256;                                  \
  int tid = threadIdx.x;                                                           \
  int wid = tid >> 6, l = tid & 63, l15 = l & 15, lh = l >> 4;                     \
  int s7 = l15 & 7;                                                                \
  int wr = wid >> 2, wc = wid & 3;                                                 \
  const short* Ab = A + (size_t)m0 * K;                                            \
  const short* Bb = Bt + (size_t)n0 * K;                                           \
  f4v z = {0.f, 0.f, 0.f, 0.f};                                                    \
  f4v acc[8][4];                                                                   \
  _Pragma("unroll") for (int i = 0; i < 8; ++i)                                    \
    _Pragma("unroll") for (int j = 0; j < 4; ++j) acc[i][j] = z;                   \
  s8v af[4][2], bf0[2][2], bf1[2][2];                                              \
  int NT = K >> 6;                                                                 \
  STAGE_HALF(Ab, sA, 0, 0, 0); STAGE_HALF(Ab, sA, 0, 1, 0);                        \
  STAGE_HALF(Bb, sB, 0, 0, 0); STAGE_HALF(Bb, sB, 0, 1, 0);                        \
  STAGE_HALF(Ab, sA, 1, 0, 1); STAGE_HALF(Bb, sB, 1, 0, 1);                        \
  STAGE_HALF(Bb, sB, 1, 1, 1);                                                     \
  asm volatile("s_waitcnt vmcnt(6)" ::: "memory");                                 \
  BARR;                                                                            \
  int cur = 0;                                                                     \
  for (int kt = 0; kt < NT; ++kt) {                                                \
    int nxt = cur ^ 1;                                                             \
    /* ph1: quadrant (A-half0, B-lo); stage deferred A1 of kt+1 into nxt */        \
    READ_A(0); READ_B(bf0, 0);                                                     \
    if (kt + 1 < NT) STAGE_HALF(Ab, sA, nxt, 1, kt + 1);                           \
    BARR; DO_MFMA(0, 0, bf0); BARR;                                                \
    /* ph2: (A-half0, B-hi); stage A0 of kt+2 into cur (A-half0 consumed ph1) */   \
    READ_B(bf1, 1);                                                                \
    if (kt + 2 < NT) STAGE_HALF(Ab, sA, cur, 0, kt + 2);                           \
    BARR; DO_MFMA(0, 1, bf1); BARR;                                                \
    /* ph3: (A-half1, B-hi); stage B0 of kt+2 (all B reads done by ph2) */         \
    READ_A(1);                                                                     \
    if (kt + 2 < NT) STAGE_HALF(Bb, sB, cur, 0, kt + 2);                           \
    BARR; DO_MFMA(1, 1, bf1); BARR;                                                \
    /* ph4: (A-half1, B-lo); stage B1 of kt+2 */                                   \
    if (kt + 2 < NT) STAGE_HALF(Bb, sB, cur, 1, kt + 2);                           \
    BARR; DO_MFMA(1, 0, bf0);                                                      \
    if (kt < NT - 2)       { asm volatile("s_waitcnt vmcnt(6)" ::: "memory"); }    \
    else if (kt == NT - 2) { asm volatile("s_waitcnt vmcnt(0)" ::: "memory"); }    \
    BARR;                                                                          \
    cur = nxt;                                                                     \
  }

// ---------------- 256² GEMM + bias + GELU (sigmoid-form) -> bf16 ----------------
__global__ __launch_bounds__(512, 1) void gemm_gelu(const short* __restrict__ A, const short* __restrict__ Bt,
                                                    const float* __restrict__ bias, short* __restrict__ C,
                                                    int M, int N, int K) {
  __shared__ __align__(16) short sA[2][256][64];
  __shared__ __align__(16) short sB[2][256][64];
  GEMM8_BODY
#pragma unroll
  for (int ri = 0; ri < 8; ++ri)
#pragma unroll
    for (int ci = 0; ci < 4; ++ci) {
      int col = n0 + wc * 64 + (ci >> 1) * 32 + (ci & 1) * 16 + l15;
      float bi = bias[col];
#pragma unroll
      for (int i = 0; i < 4; ++i) {
        int row = m0 + (ri >> 2) * 128 + wr * 64 + (ri & 3) * 16 + lh * 4 + i;
        float v = acc[ri][ci][i] + bi;
        float u = v * (2.30221838f + 0.10294364f * v * v);
        v = v / (1.f + exp2f(-u));
        C[(size_t)row * N + col] = f2bf(v);
      }
    }
}

// ---------------- 256² GEMM + bias + residual (in-place on out) ----------------
__global__ __launch_bounds__(512, 1) void gemm_res(const short* __restrict__ A, const short* __restrict__ Bt,
                                                   const float* __restrict__ bias, float* __restrict__ outp,
                                                   int Mvalid, int N, int K) {
  __shared__ __align__(16) short sA[2][256][64];
  __shared__ __align__(16) short sB[2][256][64];
  GEMM8_BODY
#pragma unroll
  for (int ri = 0; ri < 8; ++ri)
#pragma unroll
    for (int ci = 0; ci < 4; ++ci) {
      int col = n0 + wc * 64 + (ci >> 1) * 32 + (ci & 1) * 16 + l15;
      float bi = bias[col];
#pragma unroll
      for (int i = 0; i < 4; ++i) {
        int row = m0 + (ri >> 2) * 128 + wr * 64 + (ri & 3) * 16 + lh * 4 + i;
        if (row < Mvalid) {
          size_t idx = (size_t)row * N + col;
          outp[idx] += acc[ri][ci][i] + bi;
        }
      }
    }
}

extern "C" void kernel_launch(void* const* d_in, const int* in_sizes, int n_in,
                              void* d_out, int out_size, void* d_ws, size_t ws_size,
                              hipStream_t stream) {
  const float* x    = (const float*)d_in[0];
  const float* ln1g = (const float*)d_in[1];
  const float* ln1b = (const float*)d_in[2];
  const float* ln2g = (const float*)d_in[3];
  const float* ln2b = (const float*)d_in[4];
  const float* wq   = (const float*)d_in[5];
  const float* bq   = (const float*)d_in[6];
  const float* wk   = (const float*)d_in[7];
  const float* bk   = (const float*)d_in[8];
  const float* wv   = (const float*)d_in[9];
  const float* bv   = (const float*)d_in[10];
  const float* w1   = (const float*)d_in[11];
  const float* b1   = (const float*)d_in[12];
  const float* w2   = (const float*)d_in[13];
  const float* b2   = (const float*)d_in[14];
  float* outp = (float*)d_out;

  // ---- workspace layout with aliasing (peak ~154 MiB) ----
  char* ws = (char*)d_ws;
  size_t off = 0;
  auto carve = [&](size_t elems) -> short* {
    short* p = (short*)(ws + off);
    off += elems * sizeof(short);
    off = (off + 255) & ~(size_t)255;
    return p;
  };
  short* yn   = carve((size_t)MPAD * DMODEL);
  short* w1t  = carve((size_t)MLPD * DMODEL);
  short* w2t  = carve((size_t)DMODEL * MLPD);
  short* wqt  = carve((size_t)NH * 64 * 64);
  short* wkt  = carve((size_t)NH * 64 * 64);
  short* wvt  = carve((size_t)NH * 64 * 64);
  size_t union_base = off;
  short* hbuf = carve((size_t)MPAD * MLPD);           // phase B
  off = union_base;                                    // phase A aliases
  short* xn   = carve((size_t)NROWS * DMODEL);
  short* qg   = carve((size_t)NBH * S_LEN * DHEAD);
  short* kg   = carve((size_t)NBH * S_LEN * DHEAD);
  short* vtb  = carve((size_t)NBH * DHEAD * SPAD);
  (void)ws_size; (void)in_sizes; (void)n_in; (void)out_size;

  // prep weights
  transpose_w<<<dim3(MLPD / 32, DMODEL / 32), dim3(32, 8), 0, stream>>>(w1, w1t, DMODEL, MLPD);
  transpose_w<<<dim3(DMODEL / 32, MLPD / 32), dim3(32, 8), 0, stream>>>(w2, w2t, MLPD, DMODEL);
  prep_qkv<<<NH, 256, 0, stream>>>(wq, wk, wv, wqt, wkt, wvt);
  pad_vt<<<(NBH * DHEAD * (SPAD - S_LEN) + 255) / 256, 256, 0, stream>>>(vtb);

  // LN1 -> xn (bf16)
  ln_kernel<<<NROWS, 256, 0, stream>>>(x, ln1g, ln1b, xn);

  // QKV projections (V transposed to [bh][d][s])
  qkv_kernel<<<((NROWS + 63) / 64) * NH, 256, 0, stream>>>(xn, wqt, wkt, wvt, bq, bk, bv, qg, kg, vtb);

  // attention + residual1 -> d_out
  attn_kernel<<<dim3(NBH, 5), 256, 0, stream>>>(qg, kg, vtb, x, outp);

  // LN2 -> yn
  ln_kernel<<<NROWS, 256, 0, stream>>>(outp, ln2g, ln2b, yn);

  // MLP (256² 8-phase kernels; 1-D grids, XCD-chunked inside)
  gemm_gelu<<<dim3((MPAD / 256) * (MLPD / 256)), 512, 0, stream>>>(yn, w1t, b1, hbuf, MPAD, MLPD, DMODEL);
  gemm_res<<<dim3((MPAD / 256) * (DMODEL / 256)), 512, 0, stream>>>(hbuf, w2t, b2, outp, NROWS, DMODEL, MLPD);
}

// Round 10
// 528.251 us; speedup vs baseline: 1.5397x; 1.0160x over previous
//
#include <hip/hip_runtime.h>

#define S_LEN 577
#define SPAD  640
#define DMODEL 768
#define NH 12
#define DHEAD 64
#define MLPD 3072
#define NROWS (32 * 577)      // 18464
#define MPAD  18688           // 73*256
#define NBH   (32 * 12)       // 384
#define LOG2E 1.44269504088896340736f

typedef __attribute__((ext_vector_type(8))) short s8v;
typedef __attribute__((ext_vector_type(4))) float f4v;

#define MFMA16(a, b, c) __builtin_amdgcn_mfma_f32_16x16x32_bf16((a), (b), (c), 0, 0, 0)

__device__ __forceinline__ short f2bf(float f) {
  union { float f; unsigned u; } a; a.f = f;
  unsigned r = a.u + 0x7FFFu + ((a.u >> 16) & 1u);
  return (short)(r >> 16);
}
// round-half-up bf16 (2 ops) — used on softmax P values
__device__ __forceinline__ short f2bfF(float f) {
  union { float f; unsigned u; } a; a.f = f;
  return (short)((a.u + 0x8000u) >> 16);
}

__device__ __forceinline__ void gload16(const short* g, const short* l) {
  __builtin_amdgcn_global_load_lds(
      (const __attribute__((address_space(1))) void*)g,
      (__attribute__((address_space(3))) void*)l, 16, 0, 0);
}

// ---------------- prep: transpose fp32 (R,C) -> bf16 (C,R) ----------------
__global__ __launch_bounds__(256) void transpose_w(const float* __restrict__ in,
                                                   short* __restrict__ out, int R, int C) {
  __shared__ float tile[32][33];
  int c0 = blockIdx.x * 32, r0 = blockIdx.y * 32;
  int tx = threadIdx.x, ty = threadIdx.y;
  for (int i = ty; i < 32; i += 8) tile[i][tx] = in[(size_t)(r0 + i) * C + c0 + tx];
  __syncthreads();
  for (int i = ty; i < 32; i += 8) out[(size_t)(c0 + i) * R + r0 + tx] = f2bf(tile[tx][i]);
}

// ---------------- prep: per-head (d,o) -> bf16 (o,d) for wq/wk/wv ----------------
__global__ __launch_bounds__(256) void prep_qkv(const float* __restrict__ wq, const float* __restrict__ wk,
                                                const float* __restrict__ wv, short* __restrict__ oq,
                                                short* __restrict__ ok, short* __restrict__ ov) {
  int h = blockIdx.x, t = threadIdx.x;
  const float* src0 = wq + (size_t)h * 4096;
  const float* src1 = wk + (size_t)h * 4096;
  const float* src2 = wv + (size_t)h * 4096;
  short* dst0 = oq + (size_t)h * 4096;
  short* dst1 = ok + (size_t)h * 4096;
  short* dst2 = ov + (size_t)h * 4096;
  for (int i = t; i < 4096; i += 256) {
    int o = i >> 6, d = i & 63;
    dst0[i] = f2bf(src0[d * 64 + o]);
    dst1[i] = f2bf(src1[d * 64 + o]);
    dst2[i] = f2bf(src2[d * 64 + o]);
  }
}

// ------- zero the s-padding of vt [NBH][64][SPAD] and kg [NBH][SPAD][64], s in [577,640) -------
__global__ __launch_bounds__(256) void pad_kv(short* __restrict__ kg, short* __restrict__ vt) {
  int idx = blockIdx.x * 256 + threadIdx.x;
  const int padw = SPAD - S_LEN;          // 63
  const int per = DHEAD * padw;           // 4032
  if (idx >= NBH * per) return;
  int bh = idx / per, r = idx - bh * per;
  int col = r / padw, s = S_LEN + (r - col * padw);
  vt[((size_t)bh * DHEAD + col) * SPAD + s] = 0;
  kg[((size_t)bh * SPAD + s) * DHEAD + col] = 0;
}

// ---------------- LayerNorm (D=768), fp32 in -> bf16 out ----------------
__global__ __launch_bounds__(256) void ln_kernel(const float* __restrict__ x, const float* __restrict__ g,
                                                 const float* __restrict__ bta, short* __restrict__ out) {
  int row = blockIdx.x;
  int t = threadIdx.x;
  const float* xr = x + (size_t)row * DMODEL;
  float v0 = xr[t], v1 = xr[t + 256], v2 = xr[t + 512];
  float s = v0 + v1 + v2;
  float s2 = v0 * v0 + v1 * v1 + v2 * v2;
  for (int o = 32; o; o >>= 1) { s += __shfl_down(s, o); s2 += __shfl_down(s2, o); }
  __shared__ float red[8];
  if ((t & 63) == 0) { int w = t >> 6; red[w] = s; red[4 + w] = s2; }
  __syncthreads();
  s = red[0] + red[1] + red[2] + red[3];
  s2 = red[4] + red[5] + red[6] + red[7];
  float m = s * (1.f / DMODEL);
  float rs = rsqrtf(s2 * (1.f / DMODEL) - m * m + 1e-5f);
  short* orow = out + (size_t)row * DMODEL;
  orow[t]       = f2bf((v0 - m) * rs * g[t]       + bta[t]);
  orow[t + 256] = f2bf((v1 - m) * rs * g[t + 256] + bta[t + 256]);
  orow[t + 512] = f2bf((v2 - m) * rs * g[t + 512] + bta[t + 512]);
}

// ---------------- QKV: per-head 64x64 GEMM, bias; q pre-scaled (1/8)*log2e; K padded, V transposed ----------------
__global__ __launch_bounds__(256) void qkv_kernel(const short* __restrict__ xn,
    const short* __restrict__ wqt, const short* __restrict__ wkt, const short* __restrict__ wvt,
    const float* __restrict__ bq, const float* __restrict__ bk, const float* __restrict__ bv,
    short* __restrict__ qg, short* __restrict__ kg, short* __restrict__ vt) {
  __shared__ __align__(16) short wl[3][64][72];
  int bid = blockIdx.x;
  int h = bid % NH, mt = bid / NH;
  int t = threadIdx.x;
  {
    int o = t >> 2, d0 = (t & 3) * 16;
    const short* s0 = wqt + (size_t)h * 4096 + o * 64 + d0;
    const short* s1 = wkt + (size_t)h * 4096 + o * 64 + d0;
    const short* s2 = wvt + (size_t)h * 4096 + o * 64 + d0;
    *(uint4*)&wl[0][o][d0]     = *(const uint4*)s0;
    *(uint4*)&wl[0][o][d0 + 8] = *(const uint4*)(s0 + 8);
    *(uint4*)&wl[1][o][d0]     = *(const uint4*)s1;
    *(uint4*)&wl[1][o][d0 + 8] = *(const uint4*)(s1 + 8);
    *(uint4*)&wl[2][o][d0]     = *(const uint4*)s2;
    *(uint4*)&wl[2][o][d0 + 8] = *(const uint4*)(s2 + 8);
  }
  __syncthreads();
  int w = t >> 6, l = t & 63, l15 = l & 15, lh = l >> 4;
  int m0 = mt * 64 + w * 16;
  if (m0 >= NROWS) return;
  f4v z = {0.f, 0.f, 0.f, 0.f};
  f4v aq[4], ak[4], av[4];
#pragma unroll
  for (int nt = 0; nt < 4; ++nt) { aq[nt] = z; ak[nt] = z; av[nt] = z; }
  const short* xrow = xn + (size_t)(m0 + l15) * DMODEL + h * DHEAD;
#pragma unroll
  for (int kk = 0; kk < 64; kk += 32) {
    s8v af = *(const s8v*)(xrow + kk + lh * 8);
#pragma unroll
    for (int nt = 0; nt < 4; ++nt) {
      s8v b0 = *(const s8v*)&wl[0][nt * 16 + l15][kk + lh * 8];
      s8v b1 = *(const s8v*)&wl[1][nt * 16 + l15][kk + lh * 8];
      s8v b2 = *(const s8v*)&wl[2][nt * 16 + l15][kk + lh * 8];
      aq[nt] = MFMA16(af, b0, aq[nt]);
      ak[nt] = MFMA16(af, b1, ak[nt]);
      av[nt] = MFMA16(af, b2, av[nt]);
    }
  }
#pragma unroll
  for (int nt = 0; nt < 4; ++nt) {
    int col = nt * 16 + l15;
    float biq = bq[h * DHEAD + col], bik = bk[h * DHEAD + col], biv = bv[h * DHEAD + col];
#pragma unroll
    for (int i = 0; i < 4; ++i) {
      int m = m0 + lh * 4 + i;
      int bb = m / S_LEN;
      int ss = m - bb * S_LEN;
      int bh = bb * NH + h;
      qg[((size_t)bh * S_LEN + ss) * DHEAD + col] = f2bf((aq[nt][i] + biq) * (0.125f * LOG2E));
      kg[((size_t)bh * SPAD + ss) * DHEAD + col]  = f2bf(ak[nt][i] + bik);
      vt[((size_t)bh * DHEAD + col) * SPAD + ss]  = f2bf(av[nt][i] + biv);
    }
  }
}

// ------- attention: flash-style, 32 q-rows/wave, K-reg prefetch, STATIC-max exp2 softmax -------
// scores are in log2 units (q pre-scaled by log2e/8); static max M0=16 folded into MFMA C-init.
__global__ __launch_bounds__(256) void attn_kernel(const short* __restrict__ qg, const short* __restrict__ kg,
                                                   const short* __restrict__ vt, const float* __restrict__ x,
                                                   float* __restrict__ outp) {
  __shared__ __align__(16) short Pb[4][32][72];
  int bh = blockIdx.x;       // 0..383
  int qt = blockIdx.y;       // 0..4
  int h = bh % NH, b = bh / NH;
  int t = threadIdx.x, w = t >> 6, l = t & 63, l15 = l & 15, lh = l >> 4;
  int q0 = qt * 128 + w * 32;
  if (q0 > 576) return;
  size_t qbase = (size_t)bh * S_LEN * DHEAD;
  size_t kbase = (size_t)bh * SPAD * DHEAD;
  size_t vbase = (size_t)bh * DHEAD * SPAD;
  s8v aq[2][2];
#pragma unroll
  for (int f = 0; f < 2; ++f) {
    int qrow = q0 + f * 16 + l15; if (qrow > 576) qrow = 576;
    const short* qp = qg + qbase + (size_t)qrow * DHEAD + lh * 8;
    aq[f][0] = *(const s8v*)qp;
    aq[f][1] = *(const s8v*)(qp + 32);
  }
  f4v z = {0.f, 0.f, 0.f, 0.f};
  f4v z16 = {-16.f, -16.f, -16.f, -16.f};   // static-max offset as C-init
  f4v acc[2][4];
  float lsum[2][4];
#pragma unroll
  for (int f = 0; f < 2; ++f) {
#pragma unroll
    for (int dt = 0; dt < 4; ++dt) acc[f][dt] = z;
#pragma unroll
    for (int i = 0; i < 4; ++i) lsum[f][i] = 0.f;
  }

#define LOADK(KB, K0, K1)                                              \
  {                                                                    \
    _Pragma("unroll")                                                  \
    for (int nt = 0; nt < 4; ++nt) {                                   \
      const short* kp = kg + kbase + (size_t)((KB) + nt * 16 + l15) * DHEAD + lh * 8; \
      K0[nt] = *(const s8v*)kp;                                        \
      K1[nt] = *(const s8v*)(kp + 32);                                 \
    }                                                                  \
  }

  s8v kf0[4], kf1[4];
  LOADK(0, kf0, kf1);

  for (int kt = 0; kt < 10; ++kt) {
    int kb = kt * 64;
    // ---- QK^T (C pre-initialized to -16 => scores come out already shifted) ----
    f4v sc[2][4];
#pragma unroll
    for (int nt = 0; nt < 4; ++nt) {
#pragma unroll
      for (int f = 0; f < 2; ++f) {
        f4v a = MFMA16(aq[f][0], kf0[nt], z16);
        a = MFMA16(aq[f][1], kf1[nt], a);
        sc[f][nt] = a;
      }
    }
    // ---- prefetch next K tile ----
    s8v kn0[4], kn1[4];
    if (kt < 9) LOADK(kb + 64, kn0, kn1);
    if (kt == 9) {
#pragma unroll
      for (int nt = 0; nt < 4; ++nt) {
        int col = kb + nt * 16 + l15;
        if (col > 576) {
#pragma unroll
          for (int f = 0; f < 2; ++f) { sc[f][nt][0] = sc[f][nt][1] = sc[f][nt][2] = sc[f][nt][3] = -1e30f; }
        }
      }
    }
    // ---- static-max softmax: P = exp2(sc), per-lane partial sums (reduced once at end) ----
#pragma unroll
    for (int f = 0; f < 2; ++f)
#pragma unroll
      for (int i = 0; i < 4; ++i) {
        float s = lsum[f][i];
#pragma unroll
        for (int nt = 0; nt < 4; ++nt) {
          float e = exp2f(sc[f][nt][i]);
          s += e;
          Pb[w][f * 16 + lh * 4 + i][nt * 16 + l15] = f2bfF(e);
        }
        lsum[f][i] = s;
      }
    // ---- PV: O += P @ V ----
#pragma unroll
    for (int kk2 = 0; kk2 < 2; ++kk2) {
      const short* vp = vt + vbase + kb + kk2 * 32 + lh * 8;
      s8v af0 = *(const s8v*)&Pb[w][l15][kk2 * 32 + lh * 8];
      s8v af1 = *(const s8v*)&Pb[w][16 + l15][kk2 * 32 + lh * 8];
#pragma unroll
      for (int dt = 0; dt < 4; ++dt) {
        s8v bf = *(const s8v*)(vp + (size_t)(dt * 16 + l15) * SPAD);
        acc[0][dt] = MFMA16(af0, bf, acc[0][dt]);
        acc[1][dt] = MFMA16(af1, bf, acc[1][dt]);
      }
    }
#pragma unroll
    for (int nt = 0; nt < 4; ++nt) { kf0[nt] = kn0[nt]; kf1[nt] = kn1[nt]; }
  }
#undef LOADK
  // ---- epilogue: single sum-reduce per row, normalize + residual ----
#pragma unroll
  for (int f = 0; f < 2; ++f)
#pragma unroll
    for (int i = 0; i < 4; ++i) {
      float s = lsum[f][i];
      s += __shfl_xor(s, 1);
      s += __shfl_xor(s, 2);
      s += __shfl_xor(s, 4);
      s += __shfl_xor(s, 8);
      int srow = q0 + f * 16 + lh * 4 + i;
      if (srow > 576) continue;
      float inv = 1.f / s;
      size_t idx0 = ((size_t)b * S_LEN + srow) * DMODEL + h * DHEAD + l15;
#pragma unroll
      for (int dt = 0; dt < 4; ++dt) {
        size_t idx = idx0 + dt * 16;
        outp[idx] = x[idx] + acc[f][dt][i] * inv;
      }
    }
}

// ================= 256x256 8-phase GEMM (T2+T3+T4+T5), 512 thr, BK=64, 128KB LDS ================
#define BARR asm volatile("s_barrier" ::: "memory")

#define STAGE_HALF(G, SH, bufi, half, ktile)                                       \
  do {                                                                             \
    _Pragma("unroll") for (int rd = 0; rd < 2; ++rd) {                             \
      int rw_ = rd * 64 + (tid >> 3);                                              \
      int sl_ = (tid & 7) ^ (rw_ & 7);                                             \
      gload16((G) + (size_t)((half) * 128 + rw_) * K + (ktile) * 64 + sl_ * 8,     \
              &SH[bufi][(half) * 128 + rw_][(tid & 7) * 8]);                       \
    }                                                                              \
  } while (0)

#define READ_A(rh)                                                                 \
  _Pragma("unroll") for (int mt = 0; mt < 4; ++mt)                                 \
    _Pragma("unroll") for (int kh = 0; kh < 2; ++kh)                               \
      af[mt][kh] = *(const s8v*)&sA[cur][(rh) * 128 + wr * 64 + mt * 16 + l15]     \
                                    [((kh * 4 + lh) ^ s7) * 8];

#define READ_B(BF, chh)                                                            \
  _Pragma("unroll") for (int nt = 0; nt < 2; ++nt)                                 \
    _Pragma("unroll") for (int kh = 0; kh < 2; ++kh)                               \
      BF[nt][kh] = *(const s8v*)&sB[cur][wc * 64 + (chh) * 32 + nt * 16 + l15]     \
                                    [((kh * 4 + lh) ^ s7) * 8];

#define DO_MFMA(rh, ch, BF)                                                        \
  __builtin_amdgcn_s_setprio(1);                                                   \
  _Pragma("unroll") for (int mt = 0; mt < 4; ++mt)                                 \
    _Pragma("unroll") for (int nt = 0; nt < 2; ++nt)                               \
      _Pragma("unroll") for (int kh = 0; kh < 2; ++kh)                             \
        acc[(rh) * 4 + mt][(ch) * 2 + nt] =                                        \
            MFMA16(af[mt][kh], BF[nt][kh], acc[(rh) * 4 + mt][(ch) * 2 + nt]);     \
  __builtin_amdgcn_s_setprio(0);

#define GEMM8_BODY                                                                 \
  int nwg = gridDim.x;                                                             \
  int orig = blockIdx.x;                                                           \
  int qq = nwg >> 3, rr = nwg & 7;                                                 \
  int xcd = orig & 7, lin = orig >> 3;                                             \
  int wg = (xcd < rr ? xcd * (qq + 1) : rr * (qq + 1) + (xcd - rr) * qq) + lin;    \
  int nx = N >> 8;                                                                 \
  int n0 = (wg % nx) * 256, m0 = (wg / nx) * 256;                                  \
  int tid = threadIdx.x;                                                           \
  int wid = tid >> 6, l = tid & 63, l15 = l & 15, lh = l >> 4;                     \
  int s7 = l15 & 7;                                                                \
  int wr = wid >> 2, wc = wid & 3;                                                 \
  const short* Ab = A + (size_t)m0 * K;                                            \
  const short* Bb = Bt + (size_t)n0 * K;                                           \
  f4v z = {0.f, 0.f, 0.f, 0.f};                                                    \
  f4v acc[8][4];                                                                   \
  _Pragma("unroll") for (int i = 0; i < 8; ++i)                                    \
    _Pragma("unroll") for (int j = 0; j < 4; ++j) acc[i][j] = z;                   \
  s8v af[4][2], bf0[2][2], bf1[2][2];                                              \
  int NT = K >> 6;                                                                 \
  STAGE_HALF(Ab, sA, 0, 0, 0); STAGE_HALF(Ab, sA, 0, 1, 0);                        \
  STAGE_HALF(Bb, sB, 0, 0, 0); STAGE_HALF(Bb, sB, 0, 1, 0);                        \
  STAGE_HALF(Ab, sA, 1, 0, 1); STAGE_HALF(Bb, sB, 1, 0, 1);                        \
  STAGE_HALF(Bb, sB, 1, 1, 1);                                                     \
  asm volatile("s_waitcnt vmcnt(6)" ::: "memory");                                 \
  BARR;                                                                            \
  int cur = 0;                                                                     \
  for (int kt = 0; kt < NT; ++kt) {                                                \
    int nxt = cur ^ 1;                                                             \
    READ_A(0); READ_B(bf0, 0);                                                     \
    if (kt + 1 < NT) STAGE_HALF(Ab, sA, nxt, 1, kt + 1);                           \
    BARR; DO_MFMA(0, 0, bf0); BARR;                                                \
    READ_B(bf1, 1);                                                                \
    if (kt + 2 < NT) STAGE_HALF(Ab, sA, cur, 0, kt + 2);                           \
    BARR; DO_MFMA(0, 1, bf1); BARR;                                                \
    READ_A(1);                                                                     \
    if (kt + 2 < NT) STAGE_HALF(Bb, sB, cur, 0, kt + 2);                           \
    BARR; DO_MFMA(1, 1, bf1); BARR;                                                \
    if (kt + 2 < NT) STAGE_HALF(Bb, sB, cur, 1, kt + 2);                           \
    BARR; DO_MFMA(1, 0, bf0);                                                      \
    if (kt < NT - 2)       { asm volatile("s_waitcnt vmcnt(6)" ::: "memory"); }    \
    else if (kt == NT - 2) { asm volatile("s_waitcnt vmcnt(0)" ::: "memory"); }    \
    BARR;                                                                          \
    cur = nxt;                                                                     \
  }

// ---------------- 256² GEMM + bias + GELU (sigmoid-form) -> bf16 ----------------
__global__ __launch_bounds__(512, 1) void gemm_gelu(const short* __restrict__ A, const short* __restrict__ Bt,
                                                    const float* __restrict__ bias, short* __restrict__ C,
                                                    int M, int N, int K) {
  __shared__ __align__(16) short sA[2][256][64];
  __shared__ __align__(16) short sB[2][256][64];
  GEMM8_BODY
#pragma unroll
  for (int ri = 0; ri < 8; ++ri)
#pragma unroll
    for (int ci = 0; ci < 4; ++ci) {
      int col = n0 + wc * 64 + (ci >> 1) * 32 + (ci & 1) * 16 + l15;
      float bi = bias[col];
#pragma unroll
      for (int i = 0; i < 4; ++i) {
        int row = m0 + (ri >> 2) * 128 + wr * 64 + (ri & 3) * 16 + lh * 4 + i;
        float v = acc[ri][ci][i] + bi;
        float u = v * (2.30221838f + 0.10294364f * v * v);
        v = v / (1.f + exp2f(-u));
        C[(size_t)row * N + col] = f2bf(v);
      }
    }
}

// ---------------- 256² GEMM + bias + residual (in-place on out) ----------------
__global__ __launch_bounds__(512, 1) void gemm_res(const short* __restrict__ A, const short* __restrict__ Bt,
                                                   const float* __restrict__ bias, float* __restrict__ outp,
                                                   int Mvalid, int N, int K) {
  __shared__ __align__(16) short sA[2][256][64];
  __shared__ __align__(16) short sB[2][256][64];
  GEMM8_BODY
#pragma unroll
  for (int ri = 0; ri < 8; ++ri)
#pragma unroll
    for (int ci = 0; ci < 4; ++ci) {
      int col = n0 + wc * 64 + (ci >> 1) * 32 + (ci & 1) * 16 + l15;
      float bi = bias[col];
#pragma unroll
      for (int i = 0; i < 4; ++i) {
        int row = m0 + (ri >> 2) * 128 + wr * 64 + (ri & 3) * 16 + lh * 4 + i;
        if (row < Mvalid) {
          size_t idx = (size_t)row * N + col;
          outp[idx] += acc[ri][ci][i] + bi;
        }
      }
    }
}

extern "C" void kernel_launch(void* const* d_in, const int* in_sizes, int n_in,
                              void* d_out, int out_size, void* d_ws, size_t ws_size,
                              hipStream_t stream) {
  const float* x    = (const float*)d_in[0];
  const float* ln1g = (const float*)d_in[1];
  const float* ln1b = (const float*)d_in[2];
  const float* ln2g = (const float*)d_in[3];
  const float* ln2b = (const float*)d_in[4];
  const float* wq   = (const float*)d_in[5];
  const float* bq   = (const float*)d_in[6];
  const float* wk   = (const float*)d_in[7];
  const float* bk   = (const float*)d_in[8];
  const float* wv   = (const float*)d_in[9];
  const float* bv   = (const float*)d_in[10];
  const float* w1   = (const float*)d_in[11];
  const float* b1   = (const float*)d_in[12];
  const float* w2   = (const float*)d_in[13];
  const float* b2   = (const float*)d_in[14];
  float* outp = (float*)d_out;

  // ---- workspace layout with aliasing (peak ~158 MiB) ----
  char* ws = (char*)d_ws;
  size_t off = 0;
  auto carve = [&](size_t elems) -> short* {
    short* p = (short*)(ws + off);
    off += elems * sizeof(short);
    off = (off + 255) & ~(size_t)255;
    return p;
  };
  short* yn   = carve((size_t)MPAD * DMODEL);
  short* w1t  = carve((size_t)MLPD * DMODEL);
  short* w2t  = carve((size_t)DMODEL * MLPD);
  short* wqt  = carve((size_t)NH * 64 * 64);
  short* wkt  = carve((size_t)NH * 64 * 64);
  short* wvt  = carve((size_t)NH * 64 * 64);
  size_t union_base = off;
  short* hbuf = carve((size_t)MPAD * MLPD);           // phase B
  off = union_base;                                    // phase A aliases
  short* xn   = carve((size_t)NROWS * DMODEL);
  short* qg   = carve((size_t)NBH * S_LEN * DHEAD);
  short* kg   = carve((size_t)NBH * SPAD * DHEAD);    // K padded to 640 rows
  short* vtb  = carve((size_t)NBH * DHEAD * SPAD);
  (void)ws_size; (void)in_sizes; (void)n_in; (void)out_size;

  // prep weights
  transpose_w<<<dim3(MLPD / 32, DMODEL / 32), dim3(32, 8), 0, stream>>>(w1, w1t, DMODEL, MLPD);
  transpose_w<<<dim3(DMODEL / 32, MLPD / 32), dim3(32, 8), 0, stream>>>(w2, w2t, MLPD, DMODEL);
  prep_qkv<<<NH, 256, 0, stream>>>(wq, wk, wv, wqt, wkt, wvt);
  pad_kv<<<(NBH * DHEAD * (SPAD - S_LEN) + 255) / 256, 256, 0, stream>>>(kg, vtb);

  // LN1 -> xn (bf16)
  ln_kernel<<<NROWS, 256, 0, stream>>>(x, ln1g, ln1b, xn);

  // QKV projections (K padded rows, V transposed)
  qkv_kernel<<<((NROWS + 63) / 64) * NH, 256, 0, stream>>>(xn, wqt, wkt, wvt, bq, bk, bv, qg, kg, vtb);

  // attention + residual1 -> d_out
  attn_kernel<<<dim3(NBH, 5), 256, 0, stream>>>(qg, kg, vtb, x, outp);

  // LN2 -> yn
  ln_kernel<<<NROWS, 256, 0, stream>>>(outp, ln2g, ln2b, yn);

  // MLP (256² 8-phase kernels; 1-D grids, XCD-chunked inside)
  gemm_gelu<<<dim3((MPAD / 256) * (MLPD / 256)), 512, 0, stream>>>(yn, w1t, b1, hbuf, MPAD, MLPD, DMODEL);
  gemm_res<<<dim3((MPAD / 256) * (DMODEL / 256)), 512, 0, stream>>>(hbuf, w2t, b2, outp, NROWS, DMODEL, MLPD);
}